// Round 1
// baseline (281.596 us; speedup 1.0000x reference)
//
#include <hip/hip_runtime.h>
#include <hip/hip_bf16.h>

#define NB 32
#define NJ 48
#define NI 48
#define NCTX 5
#define NE 128
#define NH 256
#define NVS 32000
#define NS 96
#define NR 3072   // 2*B*J rows

typedef __attribute__((ext_vector_type(8))) short bf16x8;
typedef __attribute__((ext_vector_type(4))) float f32x4;

__device__ __forceinline__ float b2f(unsigned short u) {
  return __uint_as_float(((unsigned int)u) << 16);
}
__device__ __forceinline__ unsigned short f2b(float f) {
  __hip_bfloat16 h = __float2bfloat16(f);
  return *reinterpret_cast<unsigned short*>(&h);
}

// ---- W_vocab [256][32000] f32 -> Wvt [32000][256] bf16 (transposed) ----
__global__ void k_transpose(const float* __restrict__ Wv, unsigned short* __restrict__ Wvt) {
  __shared__ float tile[64][65];
  int t = threadIdx.x;
  int v0 = blockIdx.x * 64, k0 = blockIdx.y * 64;
  for (int it = 0; it < 16; ++it) {
    int idx = it * 256 + t;
    int kr = idx >> 6, vc = idx & 63;
    tile[kr][vc] = Wv[(k0 + kr) * NVS + v0 + vc];
  }
  __syncthreads();
  for (int it = 0; it < 16; ++it) {
    int idx = it * 256 + t;
    int vl = idx >> 6, kl = idx & 63;
    Wvt[(v0 + vl) * NH + k0 + kl] = f2b(tile[kl][vl]);
  }
}

// ---- embedding gather + bridge (640->128) + hidden (128->256) + tanh -> h bf16 [3072][256]
__global__ void k_bridge(const float* __restrict__ emb, const float* __restrict__ Wb,
                         const float* __restrict__ Wh, const float* __restrict__ bh,
                         const int* __restrict__ tc, const int* __restrict__ tcn,
                         unsigned short* __restrict__ hb) {
  __shared__ float x_lds[16][640];
  __shared__ float xb_lds[16][128];
  int t = threadIdx.x;
  int r0 = blockIdx.x * 16;
  // gather x rows: x[row][p*128+e] = emb[ids[b, j*5+p], e]
  for (int it = 0; it < 40; ++it) {
    int idx = it * 256 + t;
    int row = idx / 640, c = idx % 640;
    int r = r0 + row;
    int half = r / 1536, rem = r % 1536, b = rem / 48, j = rem % 48;
    int p = c >> 7, e = c & 127;
    const int* ids = half ? tcn : tc;
    int id = ids[b * 240 + j * 5 + p];
    x_lds[row][c] = emb[id * 128 + e];
  }
  __syncthreads();
  // xb = x @ Wb  (each thread: one e for 8 rows)
  {
    int e = t & 127, rg = t >> 7;
    float acc[8];
#pragma unroll
    for (int q = 0; q < 8; ++q) acc[q] = 0.f;
    for (int c = 0; c < 640; ++c) {
      float w = Wb[c * 128 + e];
#pragma unroll
      for (int q = 0; q < 8; ++q) acc[q] += x_lds[rg + 2 * q][c] * w;
    }
#pragma unroll
    for (int q = 0; q < 8; ++q) xb_lds[rg + 2 * q][e] = acc[q];
  }
  __syncthreads();
  // h = tanh(xb @ Wh + bh)  (each thread: one output unit o for all 16 rows)
  {
    int o = t;
    float acc[16];
#pragma unroll
    for (int rr = 0; rr < 16; ++rr) acc[rr] = 0.f;
    for (int e = 0; e < 128; ++e) {
      float w = Wh[e * 256 + o];
#pragma unroll
      for (int rr = 0; rr < 16; ++rr) acc[rr] += xb_lds[rr][e] * w;
    }
    float bias = bh[o];
#pragma unroll
    for (int rr = 0; rr < 16; ++rr) {
      float hv = tanhf(acc[rr] + bias);
      hb[(r0 + rr) * 256 + o] = f2b(hv);
    }
  }
}

// ---- denominator GEMM: rowsum of exp(h @ Wv + bv), bf16 MFMA, 128x128 tiles ----
__global__ __launch_bounds__(256) void k_denom(const unsigned short* __restrict__ hb,
                                               const unsigned short* __restrict__ Wvt,
                                               const float* __restrict__ bv,
                                               float* __restrict__ dpart) {
  __shared__ unsigned short Asm[128 * 72];
  __shared__ unsigned short Bsm[128 * 72];
  __shared__ float red2[2][128];
  int t = threadIdx.x;
  int vt = blockIdx.x;           // 250 vocab tiles
  int rt = blockIdx.y;           // 24 row tiles
  int v0 = vt * 128, r0 = rt * 128;
  int wave = t >> 6, lane = t & 63;
  int wm = wave >> 1, wn = wave & 1;
  int lg = lane >> 4, lr = lane & 15;

  f32x4 acc[4][4];
#pragma unroll
  for (int m = 0; m < 4; ++m)
#pragma unroll
    for (int n = 0; n < 4; ++n) acc[m][n] = (f32x4){0.f, 0.f, 0.f, 0.f};

  for (int k0 = 0; k0 < 256; k0 += 64) {
#pragma unroll
    for (int it = 0; it < 4; ++it) {
      int idx = it * 256 + t;
      int row = idx >> 3, seg = idx & 7;
      *(uint4*)&Asm[row * 72 + seg * 8] = *(const uint4*)&hb[(r0 + row) * 256 + k0 + seg * 8];
      *(uint4*)&Bsm[row * 72 + seg * 8] = *(const uint4*)&Wvt[(v0 + row) * 256 + k0 + seg * 8];
    }
    __syncthreads();
#pragma unroll
    for (int kk = 0; kk < 2; ++kk) {
      bf16x8 a[4], b[4];
#pragma unroll
      for (int m = 0; m < 4; ++m)
        a[m] = *(const bf16x8*)&Asm[(wm * 64 + m * 16 + lr) * 72 + kk * 32 + lg * 8];
#pragma unroll
      for (int n = 0; n < 4; ++n)
        b[n] = *(const bf16x8*)&Bsm[(wn * 64 + n * 16 + lr) * 72 + kk * 32 + lg * 8];
#pragma unroll
      for (int m = 0; m < 4; ++m)
#pragma unroll
        for (int n = 0; n < 4; ++n)
          acc[m][n] = __builtin_amdgcn_mfma_f32_16x16x32_bf16(a[m], b[n], acc[m][n], 0, 0, 0);
    }
    __syncthreads();
  }

  // epilogue: exp + rowsum within tile
  float rs[4][4];  // [fm][reg]
#pragma unroll
  for (int m = 0; m < 4; ++m)
#pragma unroll
    for (int g = 0; g < 4; ++g) rs[m][g] = 0.f;
#pragma unroll
  for (int m = 0; m < 4; ++m) {
#pragma unroll
    for (int n = 0; n < 4; ++n) {
      float bvv = bv[v0 + wn * 64 + n * 16 + lr];
#pragma unroll
      for (int g = 0; g < 4; ++g) rs[m][g] += __expf(acc[m][n][g] + bvv);
    }
  }
#pragma unroll
  for (int m = 0; m < 4; ++m)
#pragma unroll
    for (int g = 0; g < 4; ++g) {
      float v = rs[m][g];
      v += __shfl_xor(v, 1);
      v += __shfl_xor(v, 2);
      v += __shfl_xor(v, 4);
      v += __shfl_xor(v, 8);
      rs[m][g] = v;
    }
  if (lr == 0) {
#pragma unroll
    for (int m = 0; m < 4; ++m)
#pragma unroll
      for (int g = 0; g < 4; ++g)
        red2[wn][wm * 64 + m * 16 + lg * 4 + g] = rs[m][g];
  }
  __syncthreads();
  if (t < 128) dpart[vt * NR + r0 + t] = red2[0][t] + red2[1][t];
}

// ---- reduce partial denominators ----
__global__ void k_reduce(const float* __restrict__ dpart, float* __restrict__ dsum) {
  int r = blockIdx.x * 256 + threadIdx.x;
  float s = 0.f;
  for (int vt = 0; vt < 250; ++vt) s += dpart[vt * NR + r];
  dsum[r] = s;
}

// ---- numerators + emission assembly: em[b][s][i] = exp(h.Wv[:,src]+bv[src]) / D ----
__global__ void k_emis(const unsigned short* __restrict__ hb, const unsigned short* __restrict__ Wvt,
                       const float* __restrict__ bv, const float* __restrict__ dsum,
                       const int* __restrict__ src, float* __restrict__ em) {
  __shared__ unsigned short hrow[256];
  int t = threadIdx.x;
  int r = blockIdx.x;
  hrow[t] = hb[r * 256 + t];
  __syncthreads();
  if (t < 192) {
    int i = t >> 2, q = t & 3;
    int half = r / 1536, rem = r % 1536, b = rem / 48, j = rem % 48;
    int sv = src[b * 48 + i];
    const ushort4* wp = (const ushort4*)&Wvt[sv * 256 + q * 64];
    float acc = 0.f;
#pragma unroll
    for (int it = 0; it < 16; ++it) {
      ushort4 wv = wp[it];
      int kb = q * 64 + it * 4;
      acc += b2f(hrow[kb]) * b2f(wv.x) + b2f(hrow[kb + 1]) * b2f(wv.y) +
             b2f(hrow[kb + 2]) * b2f(wv.z) + b2f(hrow[kb + 3]) * b2f(wv.w);
    }
    acc += __shfl_xor(acc, 1);
    acc += __shfl_xor(acc, 2);
    if (q == 0) {
      float val = __expf(acc + bv[sv]) / dsum[r];
      em[b * (NS * NI) + (half * 48 + j) * NI + i] = val;
    }
  }
}

// ---- scaled HMM forward-backward, one block per batch ----
__global__ __launch_bounds__(128) void k_scan(const float* __restrict__ Atr, const float* __restrict__ pi,
                                              const float* __restrict__ em, float* __restrict__ alph,
                                              float* __restrict__ out0, float* __restrict__ out1) {
  __shared__ float A_lds[96 * 97];
  __shared__ float em_lds[96 * 48];
  __shared__ float acur[96];
  __shared__ float eb[96];
  __shared__ float cs[48];
  __shared__ float red[2];
  int t = threadIdx.x;
  int b = blockIdx.x;

  for (int idx = t; idx < 96 * 96; idx += 128) {
    int s = idx / 96, tt = idx % 96;
    A_lds[s * 97 + tt] = Atr[b * 9216 + idx];
  }
  for (int idx = t; idx < 96 * 48; idx += 128) em_lds[idx] = em[b * 4608 + idx];
  __syncthreads();

  // forward i=0
  {
    float v = 0.f;
    if (t < 96) v = pi[b * 96 + t] * em_lds[t * 48 + 0];
    float ws = v;
#pragma unroll
    for (int off = 32; off > 0; off >>= 1) ws += __shfl_xor(ws, off);
    if ((t & 63) == 0) red[t >> 6] = ws;
    __syncthreads();
    float c = red[0] + red[1];
    if (t < 96) {
      float a = v / c;
      acur[t] = a;
      alph[b * 4608 + 0 * 96 + t] = a;
    }
    if (t == 0) cs[0] = c;
    __syncthreads();
  }
  // forward i=1..47
  for (int i = 1; i < 48; ++i) {
    float an = 0.f;
    if (t < 96) {
      for (int s = 0; s < 96; ++s) an += acur[s] * A_lds[s * 97 + t];
      an *= em_lds[t * 48 + i];
    }
    float ws = (t < 96) ? an : 0.f;
#pragma unroll
    for (int off = 32; off > 0; off >>= 1) ws += __shfl_xor(ws, off);
    if ((t & 63) == 0) red[t >> 6] = ws;
    __syncthreads();
    float c = red[0] + red[1];
    if (t < 96) {
      float a = an / c;
      acur[t] = a;
      alph[b * 4608 + i * 96 + t] = a;
    }
    if (t == 0) cs[i] = c;
    __syncthreads();
  }

  // loglik
  {
    float lv = (t < 48) ? logf(cs[t]) : 0.f;
#pragma unroll
    for (int off = 32; off > 0; off >>= 1) lv += __shfl_xor(lv, off);
    if (t == 0) out1[b] = -lv;
  }

  // backward + gamma
  float bt = 1.f;
  if (t < 96) out0[b * 4608 + t * 48 + 47] = alph[b * 4608 + 47 * 96 + t];
  for (int i = 46; i >= 0; --i) {
    if (t < 96) eb[t] = em_lds[t * 48 + (i + 1)] * bt;
    __syncthreads();
    if (t < 96) {
      float bn = 0.f;
      for (int tt = 0; tt < 96; ++tt) bn += A_lds[t * 97 + tt] * eb[tt];
      bt = bn / cs[i + 1];
      out0[b * 4608 + t * 48 + i] = alph[b * 4608 + i * 96 + t] * bt;
    }
    __syncthreads();
  }
}

extern "C" void kernel_launch(void* const* d_in, const int* in_sizes, int n_in,
                              void* d_out, int out_size, void* d_ws, size_t ws_size,
                              hipStream_t stream) {
  const float* emb = (const float*)d_in[0];
  const float* Wb  = (const float*)d_in[1];
  const float* Wh  = (const float*)d_in[2];
  const float* bh  = (const float*)d_in[3];
  const float* Wv  = (const float*)d_in[4];
  const float* bv  = (const float*)d_in[5];
  const float* Atr = (const float*)d_in[6];
  const float* pi  = (const float*)d_in[7];
  const int* tc    = (const int*)d_in[8];
  const int* tcn   = (const int*)d_in[9];
  const int* src   = (const int*)d_in[10];

  float* out0 = (float*)d_out;
  float* out1 = out0 + NB * NS * NI;  // 147456

  char* ws = (char*)d_ws;
  unsigned short* wvt = (unsigned short*)(ws);                  // 16,384,000 B
  unsigned short* hb  = (unsigned short*)(ws + 16384000);       //  1,572,864 B
  float* dpart        = (float*)(ws + 17956864);                //  3,072,000 B
  float* dsum         = (float*)(ws + 21028864);                //     12,288 B
  float* em           = (float*)(ws + 21041152);                //    589,824 B
  float* alph         = (float*)(ws + 21630976);                //    589,824 B

  k_transpose<<<dim3(500, 4), 256, 0, stream>>>(Wv, wvt);
  k_bridge<<<192, 256, 0, stream>>>(emb, Wb, Wh, bh, tc, tcn, hb);
  k_denom<<<dim3(250, 24), 256, 0, stream>>>(hb, wvt, bv, dpart);
  k_reduce<<<12, 256, 0, stream>>>(dpart, dsum);
  k_emis<<<3072, 256, 0, stream>>>(hb, wvt, bv, dsum, src, em);
  k_scan<<<32, 128, 0, stream>>>(Atr, pi, em, alph, out0, out1);
}

// Round 2
// 227.345 us; speedup vs baseline: 1.2386x; 1.2386x over previous
//
#include <hip/hip_runtime.h>
#include <hip/hip_bf16.h>

#define NB 32
#define NJ 48
#define NI 48
#define NCTX 5
#define NE 128
#define NH 256
#define NVS 32000
#define NS 96
#define NR 3072   // 2*B*J rows

typedef __attribute__((ext_vector_type(8))) short bf16x8;
typedef __attribute__((ext_vector_type(4))) float f32x4;

__device__ __forceinline__ float b2f(unsigned short u) {
  return __uint_as_float(((unsigned int)u) << 16);
}
__device__ __forceinline__ unsigned short f2b(float f) {
  __hip_bfloat16 h = __float2bfloat16(f);
  return *reinterpret_cast<unsigned short*>(&h);
}
__device__ __forceinline__ float wave_sum(float v) {
  v += __shfl_xor(v, 1);
  v += __shfl_xor(v, 2);
  v += __shfl_xor(v, 4);
  v += __shfl_xor(v, 8);
  v += __shfl_xor(v, 16);
  v += __shfl_xor(v, 32);
  return v;
}

// ---- W_vocab [256][32000] f32 -> Wvt [32000][256] bf16 (transposed) ----
__global__ void k_transpose(const float* __restrict__ Wv, unsigned short* __restrict__ Wvt) {
  __shared__ float tile[64][65];
  int t = threadIdx.x;
  int v0 = blockIdx.x * 64, k0 = blockIdx.y * 64;
  for (int it = 0; it < 16; ++it) {
    int idx = it * 256 + t;
    int kr = idx >> 6, vc = idx & 63;
    tile[kr][vc] = Wv[(k0 + kr) * NVS + v0 + vc];
  }
  __syncthreads();
  for (int it = 0; it < 16; ++it) {
    int idx = it * 256 + t;
    int vl = idx >> 6, kl = idx & 63;
    Wvt[(v0 + vl) * NH + k0 + kl] = f2b(tile[kl][vl]);
  }
}

// ---- embedding gather + bridge (640->128) + hidden (128->256) + tanh -> h bf16 [3072][256]
__global__ void k_bridge(const float* __restrict__ emb, const float* __restrict__ Wb,
                         const float* __restrict__ Wh, const float* __restrict__ bh,
                         const int* __restrict__ tc, const int* __restrict__ tcn,
                         unsigned short* __restrict__ hb) {
  __shared__ float x_lds[16][640];
  __shared__ float xb_lds[16][128];
  int t = threadIdx.x;
  int r0 = blockIdx.x * 16;
  for (int it = 0; it < 40; ++it) {
    int idx = it * 256 + t;
    int row = idx / 640, c = idx % 640;
    int r = r0 + row;
    int half = r / 1536, rem = r % 1536, b = rem / 48, j = rem % 48;
    int p = c >> 7, e = c & 127;
    const int* ids = half ? tcn : tc;
    int id = ids[b * 240 + j * 5 + p];
    x_lds[row][c] = emb[id * 128 + e];
  }
  __syncthreads();
  {
    int e = t & 127, rg = t >> 7;
    float acc[8];
#pragma unroll
    for (int q = 0; q < 8; ++q) acc[q] = 0.f;
    for (int c = 0; c < 640; ++c) {
      float w = Wb[c * 128 + e];
#pragma unroll
      for (int q = 0; q < 8; ++q) acc[q] += x_lds[rg + 2 * q][c] * w;
    }
#pragma unroll
    for (int q = 0; q < 8; ++q) xb_lds[rg + 2 * q][e] = acc[q];
  }
  __syncthreads();
  {
    int o = t;
    float acc[16];
#pragma unroll
    for (int rr = 0; rr < 16; ++rr) acc[rr] = 0.f;
    for (int e = 0; e < 128; ++e) {
      float w = Wh[e * 256 + o];
#pragma unroll
      for (int rr = 0; rr < 16; ++rr) acc[rr] += xb_lds[rr][e] * w;
    }
    float bias = bh[o];
#pragma unroll
    for (int rr = 0; rr < 16; ++rr) {
      float hv = tanhf(acc[rr] + bias);
      hb[(r0 + rr) * 256 + o] = f2b(hv);
    }
  }
}

// ---- denominator GEMM: rowsum of exp(h @ Wv + bv), bf16 MFMA, 128x128 tiles ----
__global__ __launch_bounds__(256) void k_denom(const unsigned short* __restrict__ hb,
                                               const unsigned short* __restrict__ Wvt,
                                               const float* __restrict__ bv,
                                               float* __restrict__ dpart) {
  __shared__ unsigned short Asm[128 * 72];
  __shared__ unsigned short Bsm[128 * 72];
  __shared__ float red2[2][128];
  int t = threadIdx.x;
  int vt = blockIdx.x;
  int rt = blockIdx.y;
  int v0 = vt * 128, r0 = rt * 128;
  int wave = t >> 6, lane = t & 63;
  int wm = wave >> 1, wn = wave & 1;
  int lg = lane >> 4, lr = lane & 15;

  f32x4 acc[4][4];
#pragma unroll
  for (int m = 0; m < 4; ++m)
#pragma unroll
    for (int n = 0; n < 4; ++n) acc[m][n] = (f32x4){0.f, 0.f, 0.f, 0.f};

  for (int k0 = 0; k0 < 256; k0 += 64) {
#pragma unroll
    for (int it = 0; it < 4; ++it) {
      int idx = it * 256 + t;
      int row = idx >> 3, seg = idx & 7;
      *(uint4*)&Asm[row * 72 + seg * 8] = *(const uint4*)&hb[(r0 + row) * 256 + k0 + seg * 8];
      *(uint4*)&Bsm[row * 72 + seg * 8] = *(const uint4*)&Wvt[(v0 + row) * 256 + k0 + seg * 8];
    }
    __syncthreads();
#pragma unroll
    for (int kk = 0; kk < 2; ++kk) {
      bf16x8 a[4], b[4];
#pragma unroll
      for (int m = 0; m < 4; ++m)
        a[m] = *(const bf16x8*)&Asm[(wm * 64 + m * 16 + lr) * 72 + kk * 32 + lg * 8];
#pragma unroll
      for (int n = 0; n < 4; ++n)
        b[n] = *(const bf16x8*)&Bsm[(wn * 64 + n * 16 + lr) * 72 + kk * 32 + lg * 8];
#pragma unroll
      for (int m = 0; m < 4; ++m)
#pragma unroll
        for (int n = 0; n < 4; ++n)
          acc[m][n] = __builtin_amdgcn_mfma_f32_16x16x32_bf16(a[m], b[n], acc[m][n], 0, 0, 0);
    }
    __syncthreads();
  }

  float rs[4][4];
#pragma unroll
  for (int m = 0; m < 4; ++m)
#pragma unroll
    for (int g = 0; g < 4; ++g) rs[m][g] = 0.f;
#pragma unroll
  for (int m = 0; m < 4; ++m) {
#pragma unroll
    for (int n = 0; n < 4; ++n) {
      float bvv = bv[v0 + wn * 64 + n * 16 + lr];
#pragma unroll
      for (int g = 0; g < 4; ++g) rs[m][g] += __expf(acc[m][n][g] + bvv);
    }
  }
#pragma unroll
  for (int m = 0; m < 4; ++m)
#pragma unroll
    for (int g = 0; g < 4; ++g) {
      float v = rs[m][g];
      v += __shfl_xor(v, 1);
      v += __shfl_xor(v, 2);
      v += __shfl_xor(v, 4);
      v += __shfl_xor(v, 8);
      rs[m][g] = v;
    }
  if (lr == 0) {
#pragma unroll
    for (int m = 0; m < 4; ++m)
#pragma unroll
      for (int g = 0; g < 4; ++g)
        red2[wn][wm * 64 + m * 16 + lg * 4 + g] = rs[m][g];
  }
  __syncthreads();
  if (t < 128) dpart[vt * NR + r0 + t] = red2[0][t] + red2[1][t];
}

// ---- reduce partial denominators ----
__global__ void k_reduce(const float* __restrict__ dpart, float* __restrict__ dsum) {
  int r = blockIdx.x * 256 + threadIdx.x;
  float s = 0.f;
  for (int vt = 0; vt < 250; ++vt) s += dpart[vt * NR + r];
  dsum[r] = s;
}

// ---- numerators + emission assembly ----
__global__ void k_emis(const unsigned short* __restrict__ hb, const unsigned short* __restrict__ Wvt,
                       const float* __restrict__ bv, const float* __restrict__ dsum,
                       const int* __restrict__ src, float* __restrict__ em) {
  __shared__ unsigned short hrow[256];
  int t = threadIdx.x;
  int r = blockIdx.x;
  hrow[t] = hb[r * 256 + t];
  __syncthreads();
  if (t < 192) {
    int i = t >> 2, q = t & 3;
    int half = r / 1536, rem = r % 1536, b = rem / 48, j = rem % 48;
    int sv = src[b * 48 + i];
    const ushort4* wp = (const ushort4*)&Wvt[sv * 256 + q * 64];
    float acc = 0.f;
#pragma unroll
    for (int it = 0; it < 16; ++it) {
      ushort4 wv = wp[it];
      int kb = q * 64 + it * 4;
      acc += b2f(hrow[kb]) * b2f(wv.x) + b2f(hrow[kb + 1]) * b2f(wv.y) +
             b2f(hrow[kb + 2]) * b2f(wv.z) + b2f(hrow[kb + 3]) * b2f(wv.w);
    }
    acc += __shfl_xor(acc, 1);
    acc += __shfl_xor(acc, 2);
    if (q == 0) {
      float val = __expf(acc + bv[sv]) / dsum[r];
      em[b * (NS * NI) + (half * 48 + j) * NI + i] = val;
    }
  }
}

// ---- fused HMM forward/backward: blocks 0..31 forward(batch), 32..63 backward(batch) ----
// A held in registers (48/thread), alpha/eb vector broadcast from LDS, pair-combine via shfl.
// Backward self-normalizes per step (any per-step scale is cancelled by gamma renorm).
__global__ __launch_bounds__(192) void k_fb(const float* __restrict__ Atr, const float* __restrict__ pi,
                                            const float* __restrict__ em, float* __restrict__ alph,
                                            float* __restrict__ betas, float* __restrict__ out1) {
  __shared__ float A_st[96 * 97];                 // [s][t] padded
  __shared__ float em_lds[48 * 97];               // [i][s] padded
  __shared__ __align__(16) float vec_lds[96];     // acur (fwd) / eb (bwd)
  __shared__ float red[3];
  int t = threadIdx.x;
  int bid = blockIdx.x;
  int b = bid & 31;
  int role = bid >> 5;
  int col = t >> 1, half = t & 1;
  int base = b * 4608;

  for (int idx = t; idx < 96 * 96; idx += 192) {
    int s = idx / 96, tt = idx % 96;
    A_st[s * 97 + tt] = Atr[b * 9216 + idx];
  }
  for (int idx = t; idx < 96 * 48; idx += 192) {
    int s = idx / 48, i = idx % 48;
    em_lds[i * 97 + s] = em[base + idx];
  }
  __syncthreads();

  float Areg[48];
  if (role == 0) {
#pragma unroll
    for (int ss = 0; ss < 48; ++ss) Areg[ss] = A_st[(half * 48 + ss) * 97 + col];

    // i = 0
    float llsum;
    {
      float v = pi[b * 96 + col] * em_lds[0 * 97 + col];
      float ws = half ? 0.f : v;
      ws = wave_sum(ws);
      if ((t & 63) == 0) red[t >> 6] = ws;
      __syncthreads();
      float c = red[0] + red[1] + red[2];
      float a = v / c;
      if (!half) {
        vec_lds[col] = a;
        alph[base + col] = a;
      }
      llsum = logf(c);
      __syncthreads();
    }
    for (int i = 1; i < 48; ++i) {
      float p = 0.f;
      const float4* ap = (const float4*)&vec_lds[half * 48];
#pragma unroll
      for (int q = 0; q < 12; ++q) {
        float4 av = ap[q];
        p += av.x * Areg[4 * q] + av.y * Areg[4 * q + 1] + av.z * Areg[4 * q + 2] + av.w * Areg[4 * q + 3];
      }
      p += __shfl_xor(p, 1);
      float an = p * em_lds[i * 97 + col];
      float ws = half ? 0.f : an;
      ws = wave_sum(ws);
      if ((t & 63) == 0) red[t >> 6] = ws;
      __syncthreads();
      float c = red[0] + red[1] + red[2];
      float a = an / c;
      if (!half) {
        vec_lds[col] = a;
        alph[base + i * 96 + col] = a;
      }
      llsum += logf(c);
      __syncthreads();
    }
    if (t == 0) out1[b] = -llsum;
  } else {
#pragma unroll
    for (int tt = 0; tt < 48; ++tt) Areg[tt] = A_st[col * 97 + half * 48 + tt];

    // init: beta_47 = 1, eb = em[.,47] * 1
    if (!half) {
      betas[base + 47 * 96 + col] = 1.0f;
      vec_lds[col] = em_lds[47 * 97 + col];
    }
    __syncthreads();
    for (int i = 46; i >= 0; --i) {
      float p = 0.f;
      const float4* ep = (const float4*)&vec_lds[half * 48];
#pragma unroll
      for (int q = 0; q < 12; ++q) {
        float4 ev = ep[q];
        p += ev.x * Areg[4 * q] + ev.y * Areg[4 * q + 1] + ev.z * Areg[4 * q + 2] + ev.w * Areg[4 * q + 3];
      }
      p += __shfl_xor(p, 1);
      float ws = half ? 0.f : p;
      ws = wave_sum(ws);
      if ((t & 63) == 0) red[t >> 6] = ws;
      __syncthreads();
      float c = red[0] + red[1] + red[2];
      float bt = p / c;
      if (!half) {
        betas[base + i * 96 + col] = bt;
        vec_lds[col] = em_lds[i * 97 + col] * bt;
      }
      __syncthreads();
    }
  }
}

// ---- gamma = alpha*beta, renormalized per (b,i); write transposed [b][s][i] ----
__global__ __launch_bounds__(128) void k_gamma(const float* __restrict__ alph,
                                               const float* __restrict__ betas,
                                               float* __restrict__ out0) {
  __shared__ float red[2];
  int b = blockIdx.x, i = blockIdx.y;
  int t = threadIdx.x;
  float g = 0.f;
  if (t < 96) g = alph[b * 4608 + i * 96 + t] * betas[b * 4608 + i * 96 + t];
  float ws = wave_sum(g);
  if ((t & 63) == 0) red[t >> 6] = ws;
  __syncthreads();
  float c = red[0] + red[1];
  if (t < 96) out0[b * 4608 + t * 48 + i] = g / c;
}

extern "C" void kernel_launch(void* const* d_in, const int* in_sizes, int n_in,
                              void* d_out, int out_size, void* d_ws, size_t ws_size,
                              hipStream_t stream) {
  const float* emb = (const float*)d_in[0];
  const float* Wb  = (const float*)d_in[1];
  const float* Wh  = (const float*)d_in[2];
  const float* bh  = (const float*)d_in[3];
  const float* Wv  = (const float*)d_in[4];
  const float* bv  = (const float*)d_in[5];
  const float* Atr = (const float*)d_in[6];
  const float* pi  = (const float*)d_in[7];
  const int* tc    = (const int*)d_in[8];
  const int* tcn   = (const int*)d_in[9];
  const int* src   = (const int*)d_in[10];

  float* out0 = (float*)d_out;
  float* out1 = out0 + NB * NS * NI;

  char* ws = (char*)d_ws;
  unsigned short* wvt = (unsigned short*)(ws);                  // 16,384,000 B
  unsigned short* hb  = (unsigned short*)(ws + 16384000);       //  1,572,864 B
  float* dpart        = (float*)(ws + 17956864);                //  3,072,000 B
  float* betas        = (float*)(ws + 17956864);                //  reuse: dpart dead after k_reduce
  float* dsum         = (float*)(ws + 21028864);                //     12,288 B
  float* em           = (float*)(ws + 21041152);                //    589,824 B
  float* alph         = (float*)(ws + 21630976);                //    589,824 B

  k_transpose<<<dim3(500, 4), 256, 0, stream>>>(Wv, wvt);
  k_bridge<<<192, 256, 0, stream>>>(emb, Wb, Wh, bh, tc, tcn, hb);
  k_denom<<<dim3(250, 24), 256, 0, stream>>>(hb, wvt, bv, dpart);
  k_reduce<<<12, 256, 0, stream>>>(dpart, dsum);
  k_emis<<<3072, 256, 0, stream>>>(hb, wvt, bv, dsum, src, em);
  k_fb<<<64, 192, 0, stream>>>(Atr, pi, em, alph, betas, out1);
  k_gamma<<<dim3(32, 48), 128, 0, stream>>>(alph, betas, out0);
}

// Round 3
// 221.503 us; speedup vs baseline: 1.2713x; 1.0264x over previous
//
#include <hip/hip_runtime.h>
#include <hip/hip_bf16.h>

#define NB 32
#define NJ 48
#define NI 48
#define NCTX 5
#define NE 128
#define NH 256
#define NVS 32000
#define NS 96
#define NR 3072   // 2*B*J rows

typedef __attribute__((ext_vector_type(8))) short bf16x8;
typedef __attribute__((ext_vector_type(4))) float f32x4;

__device__ __forceinline__ float b2f(unsigned short u) {
  return __uint_as_float(((unsigned int)u) << 16);
}
__device__ __forceinline__ unsigned short f2b(float f) {
  __hip_bfloat16 h = __float2bfloat16(f);
  return *reinterpret_cast<unsigned short*>(&h);
}
__device__ __forceinline__ float wave_sum(float v) {
  v += __shfl_xor(v, 1);
  v += __shfl_xor(v, 2);
  v += __shfl_xor(v, 4);
  v += __shfl_xor(v, 8);
  v += __shfl_xor(v, 16);
  v += __shfl_xor(v, 32);
  return v;
}
__device__ __forceinline__ void gload_lds16(const void* g, void* l) {
  __builtin_amdgcn_global_load_lds(
      (const __attribute__((address_space(1))) void*)g,
      (__attribute__((address_space(3))) void*)l, 16, 0, 0);
}

// ---- W_vocab [256][32000] f32 -> Wvt [32000][256] bf16 (transposed) ----
__global__ __launch_bounds__(256) void k_transpose(const float* __restrict__ Wv,
                                                   unsigned short* __restrict__ Wvt) {
  __shared__ float tile[64][65];
  int t = threadIdx.x;
  int v0 = blockIdx.x * 64, k0 = blockIdx.y * 64;
  // loads: thread (kr = t>>4, vq = t&15) reads float4; 4 row-groups
  {
    int kr = t >> 4, vq = t & 15;
#pragma unroll
    for (int it = 0; it < 4; ++it) {
      float4 v = *(const float4*)&Wv[(k0 + kr + 16 * it) * NVS + v0 + vq * 4];
      tile[kr + 16 * it][vq * 4 + 0] = v.x;
      tile[kr + 16 * it][vq * 4 + 1] = v.y;
      tile[kr + 16 * it][vq * 4 + 2] = v.z;
      tile[kr + 16 * it][vq * 4 + 3] = v.w;
    }
  }
  __syncthreads();
  // stores: thread (vl = t>>2, kq = t&3) packs 16 shorts (32B) of column vl
  {
    int vl = t >> 2, kq = t & 3;
    unsigned short pk[16];
#pragma unroll
    for (int q = 0; q < 16; ++q) pk[q] = f2b(tile[kq * 16 + q][vl]);
    *(uint4*)&Wvt[(v0 + vl) * NH + k0 + kq * 16] = *(uint4*)&pk[0];
    *(uint4*)&Wvt[(v0 + vl) * NH + k0 + kq * 16 + 8] = *(uint4*)&pk[8];
  }
}

// ---- embedding gather + bridge (640->128) + hidden (128->256) + tanh -> h bf16 [3072][256]
__global__ void k_bridge(const float* __restrict__ emb, const float* __restrict__ Wb,
                         const float* __restrict__ Wh, const float* __restrict__ bh,
                         const int* __restrict__ tc, const int* __restrict__ tcn,
                         unsigned short* __restrict__ hb) {
  __shared__ float x_lds[16][640];
  __shared__ float xb_lds[16][128];
  int t = threadIdx.x;
  int r0 = blockIdx.x * 16;
  for (int it = 0; it < 40; ++it) {
    int idx = it * 256 + t;
    int row = idx / 640, c = idx % 640;
    int r = r0 + row;
    int half = r / 1536, rem = r % 1536, b = rem / 48, j = rem % 48;
    int p = c >> 7, e = c & 127;
    const int* ids = half ? tcn : tc;
    int id = ids[b * 240 + j * 5 + p];
    x_lds[row][c] = emb[id * 128 + e];
  }
  __syncthreads();
  {
    int e = t & 127, rg = t >> 7;
    float acc[8];
#pragma unroll
    for (int q = 0; q < 8; ++q) acc[q] = 0.f;
    for (int c = 0; c < 640; ++c) {
      float w = Wb[c * 128 + e];
#pragma unroll
      for (int q = 0; q < 8; ++q) acc[q] += x_lds[rg + 2 * q][c] * w;
    }
#pragma unroll
    for (int q = 0; q < 8; ++q) xb_lds[rg + 2 * q][e] = acc[q];
  }
  __syncthreads();
  {
    int o = t;
    float acc[16];
#pragma unroll
    for (int rr = 0; rr < 16; ++rr) acc[rr] = 0.f;
    for (int e = 0; e < 128; ++e) {
      float w = Wh[e * 256 + o];
#pragma unroll
      for (int rr = 0; rr < 16; ++rr) acc[rr] += xb_lds[rr][e] * w;
    }
    float bias = bh[o];
#pragma unroll
    for (int rr = 0; rr < 16; ++rr) {
      float hv = tanhf(acc[rr] + bias);
      hb[(r0 + rr) * 256 + o] = f2b(hv);
    }
  }
}

// ---- denominator GEMM: rowsum of exp(h @ Wv + bv), bf16 MFMA, 128x128 tiles ----
// m97 structure: global_load_lds width-16 into linear [128][64] LDS, 2-barrier loop.
// XCD-chunked 1D grid: rt-fastest within vt so 24 blocks sharing a Wvt tile run
// consecutively on the same XCD (Wvt fetched ~once into that XCD's L2).
__global__ __launch_bounds__(256) void k_denom(const unsigned short* __restrict__ hb,
                                               const unsigned short* __restrict__ Wvt,
                                               const float* __restrict__ bv,
                                               float* __restrict__ dpart) {
  __shared__ unsigned short Asm[128 * 64];
  __shared__ unsigned short Bsm[128 * 64];
  __shared__ float red2[2][128];
  int t = threadIdx.x;
  int bid = blockIdx.x;                 // 0..5999 ; 6000 = 8 * 750
  int xcd = bid & 7;
  int pos = bid >> 3;                   // 0..749
  int tile = xcd * 750 + pos;
  int vt = tile / 24, rt = tile % 24;
  int v0 = vt * 128, r0 = rt * 128;
  int wave = t >> 6, lane = t & 63;
  int wm = wave >> 1, wn = wave & 1;
  int lg = lane >> 4, lr = lane & 15;
  int srow = lane >> 3, sseg = lane & 7;   // staging: row-in-8, 16B segment

  f32x4 acc[4][4];
#pragma unroll
  for (int m = 0; m < 4; ++m)
#pragma unroll
    for (int n = 0; n < 4; ++n) acc[m][n] = (f32x4){0.f, 0.f, 0.f, 0.f};

  for (int k0 = 0; k0 < 256; k0 += 64) {
    // stage A and B via global_load_lds: per wave 4+4 instructions, 1024B each
#pragma unroll
    for (int c = 0; c < 4; ++c) {
      int inst = wave * 4 + c;               // 0..15, covers rows 8*inst..8*inst+7
      int row = inst * 8 + srow;
      gload_lds16(&hb[(r0 + row) * 256 + k0 + sseg * 8], &Asm[inst * 512]);
    }
#pragma unroll
    for (int c = 0; c < 4; ++c) {
      int inst = wave * 4 + c;
      int row = inst * 8 + srow;
      gload_lds16(&Wvt[(v0 + row) * 256 + k0 + sseg * 8], &Bsm[inst * 512]);
    }
    __syncthreads();
#pragma unroll
    for (int kk = 0; kk < 2; ++kk) {
      bf16x8 a[4], b[4];
#pragma unroll
      for (int m = 0; m < 4; ++m)
        a[m] = *(const bf16x8*)&Asm[(wm * 64 + m * 16 + lr) * 64 + kk * 32 + lg * 8];
#pragma unroll
      for (int n = 0; n < 4; ++n)
        b[n] = *(const bf16x8*)&Bsm[(wn * 64 + n * 16 + lr) * 64 + kk * 32 + lg * 8];
#pragma unroll
      for (int m = 0; m < 4; ++m)
#pragma unroll
        for (int n = 0; n < 4; ++n)
          acc[m][n] = __builtin_amdgcn_mfma_f32_16x16x32_bf16(a[m], b[n], acc[m][n], 0, 0, 0);
    }
    __syncthreads();
  }

  // epilogue: exp + rowsum within tile
  float rs[4][4];
#pragma unroll
  for (int m = 0; m < 4; ++m)
#pragma unroll
    for (int g = 0; g < 4; ++g) rs[m][g] = 0.f;
#pragma unroll
  for (int m = 0; m < 4; ++m) {
#pragma unroll
    for (int n = 0; n < 4; ++n) {
      float bvv = bv[v0 + wn * 64 + n * 16 + lr];
#pragma unroll
      for (int g = 0; g < 4; ++g) rs[m][g] += __expf(acc[m][n][g] + bvv);
    }
  }
#pragma unroll
  for (int m = 0; m < 4; ++m)
#pragma unroll
    for (int g = 0; g < 4; ++g) {
      float v = rs[m][g];
      v += __shfl_xor(v, 1);
      v += __shfl_xor(v, 2);
      v += __shfl_xor(v, 4);
      v += __shfl_xor(v, 8);
      rs[m][g] = v;
    }
  if (lr == 0) {
#pragma unroll
    for (int m = 0; m < 4; ++m)
#pragma unroll
      for (int g = 0; g < 4; ++g)
        red2[wn][wm * 64 + m * 16 + lg * 4 + g] = rs[m][g];
  }
  __syncthreads();
  if (t < 128) dpart[vt * NR + r0 + t] = red2[0][t] + red2[1][t];
}

// ---- reduce partial denominators ----
__global__ void k_reduce(const float* __restrict__ dpart, float* __restrict__ dsum) {
  int r = blockIdx.x * 256 + threadIdx.x;
  float s = 0.f;
  for (int vt = 0; vt < 250; ++vt) s += dpart[vt * NR + r];
  dsum[r] = s;
}

// ---- numerators + emission assembly ----
__global__ void k_emis(const unsigned short* __restrict__ hb, const unsigned short* __restrict__ Wvt,
                       const float* __restrict__ bv, const float* __restrict__ dsum,
                       const int* __restrict__ src, float* __restrict__ em) {
  __shared__ unsigned short hrow[256];
  int t = threadIdx.x;
  int r = blockIdx.x;
  hrow[t] = hb[r * 256 + t];
  __syncthreads();
  if (t < 192) {
    int i = t >> 2, q = t & 3;
    int half = r / 1536, rem = r % 1536, b = rem / 48, j = rem % 48;
    int sv = src[b * 48 + i];
    const ushort4* wp = (const ushort4*)&Wvt[sv * 256 + q * 64];
    float acc = 0.f;
#pragma unroll
    for (int it = 0; it < 16; ++it) {
      ushort4 wv = wp[it];
      int kb = q * 64 + it * 4;
      acc += b2f(hrow[kb]) * b2f(wv.x) + b2f(hrow[kb + 1]) * b2f(wv.y) +
             b2f(hrow[kb + 2]) * b2f(wv.z) + b2f(hrow[kb + 3]) * b2f(wv.w);
    }
    acc += __shfl_xor(acc, 1);
    acc += __shfl_xor(acc, 2);
    if (q == 0) {
      float val = __expf(acc + bv[sv]) / dsum[r];
      em[b * (NS * NI) + (half * 48 + j) * NI + i] = val;
    }
  }
}

// ---- fused HMM forward/backward: blocks 0..31 forward(batch), 32..63 backward(batch) ----
__global__ __launch_bounds__(192) void k_fb(const float* __restrict__ Atr, const float* __restrict__ pi,
                                            const float* __restrict__ em, float* __restrict__ alph,
                                            float* __restrict__ betas, float* __restrict__ out1) {
  __shared__ float A_st[96 * 97];                 // [s][t] padded
  __shared__ float em_lds[48 * 97];               // [i][s] padded
  __shared__ __align__(16) float vec_lds[96];     // acur (fwd) / eb (bwd)
  __shared__ float red[3];
  int t = threadIdx.x;
  int bid = blockIdx.x;
  int b = bid & 31;
  int role = bid >> 5;
  int col = t >> 1, half = t & 1;
  int base = b * 4608;

  for (int idx = t; idx < 96 * 96; idx += 192) {
    int s = idx / 96, tt = idx % 96;
    A_st[s * 97 + tt] = Atr[b * 9216 + idx];
  }
  for (int idx = t; idx < 96 * 48; idx += 192) {
    int s = idx / 48, i = idx % 48;
    em_lds[i * 97 + s] = em[base + idx];
  }
  __syncthreads();

  float Areg[48];
  if (role == 0) {
#pragma unroll
    for (int ss = 0; ss < 48; ++ss) Areg[ss] = A_st[(half * 48 + ss) * 97 + col];

    float llsum;
    {
      float v = pi[b * 96 + col] * em_lds[0 * 97 + col];
      float ws = half ? 0.f : v;
      ws = wave_sum(ws);
      if ((t & 63) == 0) red[t >> 6] = ws;
      __syncthreads();
      float c = red[0] + red[1] + red[2];
      float a = v / c;
      if (!half) {
        vec_lds[col] = a;
        alph[base + col] = a;
      }
      llsum = logf(c);
      __syncthreads();
    }
    for (int i = 1; i < 48; ++i) {
      float p = 0.f;
      const float4* ap = (const float4*)&vec_lds[half * 48];
#pragma unroll
      for (int q = 0; q < 12; ++q) {
        float4 av = ap[q];
        p += av.x * Areg[4 * q] + av.y * Areg[4 * q + 1] + av.z * Areg[4 * q + 2] + av.w * Areg[4 * q + 3];
      }
      p += __shfl_xor(p, 1);
      float an = p * em_lds[i * 97 + col];
      float ws = half ? 0.f : an;
      ws = wave_sum(ws);
      if ((t & 63) == 0) red[t >> 6] = ws;
      __syncthreads();
      float c = red[0] + red[1] + red[2];
      float a = an / c;
      if (!half) {
        vec_lds[col] = a;
        alph[base + i * 96 + col] = a;
      }
      llsum += logf(c);
      __syncthreads();
    }
    if (t == 0) out1[b] = -llsum;
  } else {
#pragma unroll
    for (int tt = 0; tt < 48; ++tt) Areg[tt] = A_st[col * 97 + half * 48 + tt];

    if (!half) {
      betas[base + 47 * 96 + col] = 1.0f;
      vec_lds[col] = em_lds[47 * 97 + col];
    }
    __syncthreads();
    for (int i = 46; i >= 0; --i) {
      float p = 0.f;
      const float4* ep = (const float4*)&vec_lds[half * 48];
#pragma unroll
      for (int q = 0; q < 12; ++q) {
        float4 ev = ep[q];
        p += ev.x * Areg[4 * q] + ev.y * Areg[4 * q + 1] + ev.z * Areg[4 * q + 2] + ev.w * Areg[4 * q + 3];
      }
      p += __shfl_xor(p, 1);
      float ws = half ? 0.f : p;
      ws = wave_sum(ws);
      if ((t & 63) == 0) red[t >> 6] = ws;
      __syncthreads();
      float c = red[0] + red[1] + red[2];
      float bt = p / c;
      if (!half) {
        betas[base + i * 96 + col] = bt;
        vec_lds[col] = em_lds[i * 97 + col] * bt;
      }
      __syncthreads();
    }
  }
}

// ---- gamma = alpha*beta, renormalized per (b,i); write transposed [b][s][i] ----
__global__ __launch_bounds__(128) void k_gamma(const float* __restrict__ alph,
                                               const float* __restrict__ betas,
                                               float* __restrict__ out0) {
  __shared__ float red[2];
  int b = blockIdx.x, i = blockIdx.y;
  int t = threadIdx.x;
  float g = 0.f;
  if (t < 96) g = alph[b * 4608 + i * 96 + t] * betas[b * 4608 + i * 96 + t];
  float ws = wave_sum(g);
  if ((t & 63) == 0) red[t >> 6] = ws;
  __syncthreads();
  float c = red[0] + red[1];
  if (t < 96) out0[b * 4608 + t * 48 + i] = g / c;
}

extern "C" void kernel_launch(void* const* d_in, const int* in_sizes, int n_in,
                              void* d_out, int out_size, void* d_ws, size_t ws_size,
                              hipStream_t stream) {
  const float* emb = (const float*)d_in[0];
  const float* Wb  = (const float*)d_in[1];
  const float* Wh  = (const float*)d_in[2];
  const float* bh  = (const float*)d_in[3];
  const float* Wv  = (const float*)d_in[4];
  const float* bv  = (const float*)d_in[5];
  const float* Atr = (const float*)d_in[6];
  const float* pi  = (const float*)d_in[7];
  const int* tc    = (const int*)d_in[8];
  const int* tcn   = (const int*)d_in[9];
  const int* src   = (const int*)d_in[10];

  float* out0 = (float*)d_out;
  float* out1 = out0 + NB * NS * NI;

  char* ws = (char*)d_ws;
  unsigned short* wvt = (unsigned short*)(ws);                  // 16,384,000 B
  unsigned short* hb  = (unsigned short*)(ws + 16384000);       //  1,572,864 B
  float* dpart        = (float*)(ws + 17956864);                //  3,072,000 B
  float* betas        = (float*)(ws + 17956864);                //  reuse: dpart dead after k_reduce
  float* dsum         = (float*)(ws + 21028864);                //     12,288 B
  float* em           = (float*)(ws + 21041152);                //    589,824 B
  float* alph         = (float*)(ws + 21630976);                //    589,824 B

  k_transpose<<<dim3(500, 4), 256, 0, stream>>>(Wv, wvt);
  k_bridge<<<192, 256, 0, stream>>>(emb, Wb, Wh, bh, tc, tcn, hb);
  k_denom<<<6000, 256, 0, stream>>>(hb, wvt, bv, dpart);
  k_reduce<<<12, 256, 0, stream>>>(dpart, dsum);
  k_emis<<<3072, 256, 0, stream>>>(hb, wvt, bv, dsum, src, em);
  k_fb<<<64, 192, 0, stream>>>(Atr, pi, em, alph, betas, out1);
  k_gamma<<<dim3(32, 48), 128, 0, stream>>>(alph, betas, out0);
}

// Round 4
// 205.485 us; speedup vs baseline: 1.3704x; 1.0780x over previous
//
#include <hip/hip_runtime.h>
#include <hip/hip_bf16.h>

#define NB 32
#define NJ 48
#define NI 48
#define NCTX 5
#define NE 128
#define NH 256
#define NVS 32000
#define NS 96
#define NR 3072   // 2*B*J rows

typedef __attribute__((ext_vector_type(4))) float f32x4;

__device__ __forceinline__ float wave_sum(float v) {
  v += __shfl_xor(v, 1);
  v += __shfl_xor(v, 2);
  v += __shfl_xor(v, 4);
  v += __shfl_xor(v, 8);
  v += __shfl_xor(v, 16);
  v += __shfl_xor(v, 32);
  return v;
}
__device__ __forceinline__ void gload_lds16(const void* g, void* l) {
  __builtin_amdgcn_global_load_lds(
      (const __attribute__((address_space(1))) void*)g,
      (__attribute__((address_space(3))) void*)l, 16, 0, 0);
}

// ---- W_vocab [256][32000] f32 -> Wv8 [32000][256] fp8 e4m3, scaled x64 ----
__global__ __launch_bounds__(256) void k_transpose(const float* __restrict__ Wv,
                                                   unsigned char* __restrict__ Wv8) {
  __shared__ float tile[64][65];
  int t = threadIdx.x;
  int v0 = blockIdx.x * 64, k0 = blockIdx.y * 64;
  {
    int kr = t >> 4, vq = t & 15;
#pragma unroll
    for (int it = 0; it < 4; ++it) {
      float4 v = *(const float4*)&Wv[(k0 + kr + 16 * it) * NVS + v0 + vq * 4];
      tile[kr + 16 * it][vq * 4 + 0] = v.x;
      tile[kr + 16 * it][vq * 4 + 1] = v.y;
      tile[kr + 16 * it][vq * 4 + 2] = v.z;
      tile[kr + 16 * it][vq * 4 + 3] = v.w;
    }
  }
  __syncthreads();
  {
    int vl = t >> 2, kq = t & 3;
    unsigned int q8[4];
#pragma unroll
    for (int d = 0; d < 4; ++d) {
      float f0 = tile[kq * 16 + d * 4 + 0][vl] * 64.0f;
      float f1 = tile[kq * 16 + d * 4 + 1][vl] * 64.0f;
      float f2 = tile[kq * 16 + d * 4 + 2][vl] * 64.0f;
      float f3 = tile[kq * 16 + d * 4 + 3][vl] * 64.0f;
      int w = __builtin_amdgcn_cvt_pk_fp8_f32(f0, f1, 0, false);
      w = __builtin_amdgcn_cvt_pk_fp8_f32(f2, f3, w, true);
      q8[d] = (unsigned int)w;
    }
    *(uint4*)&Wv8[(v0 + vl) * 256 + k0 + kq * 16] = *(uint4*)q8;
  }
}

// ---- embedding gather + bridge + hidden + tanh -> hb8 fp8 [3072][256], scaled x256 ----
__global__ void k_bridge(const float* __restrict__ emb, const float* __restrict__ Wb,
                         const float* __restrict__ Wh, const float* __restrict__ bh,
                         const int* __restrict__ tc, const int* __restrict__ tcn,
                         unsigned char* __restrict__ hb8) {
  __shared__ float x_lds[16][640];
  __shared__ float xb_lds[16][128];
  int t = threadIdx.x;
  int r0 = blockIdx.x * 16;
  for (int it = 0; it < 40; ++it) {
    int idx = it * 256 + t;
    int row = idx / 640, c = idx % 640;
    int r = r0 + row;
    int half = r / 1536, rem = r % 1536, b = rem / 48, j = rem % 48;
    int p = c >> 7, e = c & 127;
    const int* ids = half ? tcn : tc;
    int id = ids[b * 240 + j * 5 + p];
    x_lds[row][c] = emb[id * 128 + e];
  }
  __syncthreads();
  {
    int e = t & 127, rg = t >> 7;
    float acc[8];
#pragma unroll
    for (int q = 0; q < 8; ++q) acc[q] = 0.f;
    for (int c = 0; c < 640; ++c) {
      float w = Wb[c * 128 + e];
#pragma unroll
      for (int q = 0; q < 8; ++q) acc[q] += x_lds[rg + 2 * q][c] * w;
    }
#pragma unroll
    for (int q = 0; q < 8; ++q) xb_lds[rg + 2 * q][e] = acc[q];
  }
  __syncthreads();
  {
    int o = t;
    float acc[16];
#pragma unroll
    for (int rr = 0; rr < 16; ++rr) acc[rr] = 0.f;
    for (int e = 0; e < 128; ++e) {
      float w = Wh[e * 256 + o];
#pragma unroll
      for (int rr = 0; rr < 16; ++rr) acc[rr] += xb_lds[rr][e] * w;
    }
    float bias = bh[o];
#pragma unroll
    for (int rr = 0; rr < 16; ++rr) {
      float hv = tanhf(acc[rr] + bias);
      int p8 = __builtin_amdgcn_cvt_pk_fp8_f32(hv * 256.0f, 0.0f, 0, false);
      hb8[(r0 + rr) * 256 + o] = (unsigned char)(p8 & 0xFF);
    }
  }
}

// ---- denominator GEMM: rowsum of exp((h8 @ Wv8)*2^-14 + bv), fp8 MFMA, 128x128 ----
// Linear LDS dest for global_load_lds; XOR-swizzled (16B unit, ^row&3) on the
// per-lane GLOBAL source and on ds_read fragment addresses (rule #21 / T2).
__global__ __launch_bounds__(256) void k_denom(const unsigned char* __restrict__ hb8,
                                               const unsigned char* __restrict__ Wv8,
                                               const float* __restrict__ bv,
                                               float* __restrict__ dpart) {
  __shared__ unsigned char Asm[128 * 64];
  __shared__ unsigned char Bsm[128 * 64];
  __shared__ float red2[2][128];
  int t = threadIdx.x;
  int bid = blockIdx.x;                 // 0..5999 ; 6000 = 8 * 750
  int xcd = bid & 7;
  int pos = bid >> 3;
  int tile = xcd * 750 + pos;
  int vt = tile / 24, rt = tile % 24;
  int v0 = vt * 128, r0 = rt * 128;
  int wave = t >> 6, lane = t & 63;
  int wm = wave >> 1, wn = wave & 1;
  int lg = lane >> 4, lr = lane & 15;
  int srow = lane >> 2;                       // row within 16-row chunk
  int sseg = (lane & 3) ^ (srow & 3);         // swizzled global 16B segment

  f32x4 acc[4][4];
#pragma unroll
  for (int m = 0; m < 4; ++m)
#pragma unroll
    for (int n = 0; n < 4; ++n) acc[m][n] = (f32x4){0.f, 0.f, 0.f, 0.f};

  for (int k0 = 0; k0 < 256; k0 += 64) {
#pragma unroll
    for (int c = 0; c < 2; ++c) {
      int inst = wave * 2 + c;                // 16-row chunk index (0..7)
      int row = inst * 16 + srow;
      gload_lds16(&hb8[(r0 + row) * 256 + k0 + sseg * 16], &Asm[inst * 1024]);
      gload_lds16(&Wv8[(v0 + row) * 256 + k0 + sseg * 16], &Bsm[inst * 1024]);
    }
    __syncthreads();
#pragma unroll
    for (int kk = 0; kk < 2; ++kk) {
      long long a[4], b[4];
#pragma unroll
      for (int m = 0; m < 4; ++m) {
        int r = wm * 64 + m * 16 + lr;
        int off = r * 64 + ((((kk << 1) | (lg >> 1)) ^ (r & 3)) << 4) + ((lg & 1) << 3);
        a[m] = *(const long long*)&Asm[off];
      }
#pragma unroll
      for (int n = 0; n < 4; ++n) {
        int r = wn * 64 + n * 16 + lr;
        int off = r * 64 + ((((kk << 1) | (lg >> 1)) ^ (r & 3)) << 4) + ((lg & 1) << 3);
        b[n] = *(const long long*)&Bsm[off];
      }
#pragma unroll
      for (int m = 0; m < 4; ++m)
#pragma unroll
        for (int n = 0; n < 4; ++n)
          acc[m][n] = __builtin_amdgcn_mfma_f32_16x16x32_fp8_fp8(a[m], b[n], acc[m][n], 0, 0, 0);
    }
    __syncthreads();
  }

  const float SC = 6.103515625e-05f;  // 2^-14 (h x256, w x64)
  float rs[4][4];
#pragma unroll
  for (int m = 0; m < 4; ++m)
#pragma unroll
    for (int g = 0; g < 4; ++g) rs[m][g] = 0.f;
#pragma unroll
  for (int m = 0; m < 4; ++m) {
#pragma unroll
    for (int n = 0; n < 4; ++n) {
      float bvv = bv[v0 + wn * 64 + n * 16 + lr];
#pragma unroll
      for (int g = 0; g < 4; ++g) rs[m][g] += __expf(acc[m][n][g] * SC + bvv);
    }
  }
#pragma unroll
  for (int m = 0; m < 4; ++m)
#pragma unroll
    for (int g = 0; g < 4; ++g) {
      float v = rs[m][g];
      v += __shfl_xor(v, 1);
      v += __shfl_xor(v, 2);
      v += __shfl_xor(v, 4);
      v += __shfl_xor(v, 8);
      rs[m][g] = v;
    }
  if (lr == 0) {
#pragma unroll
    for (int m = 0; m < 4; ++m)
#pragma unroll
      for (int g = 0; g < 4; ++g)
        red2[wn][wm * 64 + m * 16 + lg * 4 + g] = rs[m][g];
  }
  __syncthreads();
  if (t < 128) dpart[vt * NR + r0 + t] = red2[0][t] + red2[1][t];
}

// ---- reduce partial denominators ----
__global__ void k_reduce(const float* __restrict__ dpart, float* __restrict__ dsum) {
  int r = blockIdx.x * 256 + threadIdx.x;
  float s = 0.f;
  for (int vt = 0; vt < 250; ++vt) s += dpart[vt * NR + r];
  dsum[r] = s;
}

// ---- emission numerators via fp8 MFMA: one 64-thread block per (b,half) ----
// 48 target rows x 48 gathered source columns, K=256. Same quantized logits as
// k_denom -> softmax of consistently perturbed logits.
__global__ __launch_bounds__(64) void k_emis(const unsigned char* __restrict__ hb8,
                                             const unsigned char* __restrict__ Wv8,
                                             const float* __restrict__ bv,
                                             const float* __restrict__ dsum,
                                             const int* __restrict__ src,
                                             float* __restrict__ em) {
  __shared__ unsigned char A8[48 * 256];
  __shared__ unsigned char B8[48 * 256];
  int t = threadIdx.x;           // 64
  int bh = blockIdx.x;           // 0..63
  int b = bh & 31, half = bh >> 5;
  int row4 = t >> 4, seg = t & 15;
  int rbase = half * 1536 + b * 48;
#pragma unroll
  for (int c = 0; c < 12; ++c) {
    int row = c * 4 + row4;
    int gseg = seg ^ (row & 15);
    gload_lds16(&hb8[(rbase + row) * 256 + gseg * 16], &A8[c * 1024]);
    int sv = src[b * 48 + row];
    gload_lds16(&Wv8[sv * 256 + gseg * 16], &B8[c * 1024]);
  }
  __syncthreads();
  int lg = t >> 4, lr = t & 15;
  f32x4 acc[3][3];
#pragma unroll
  for (int m = 0; m < 3; ++m)
#pragma unroll
    for (int n = 0; n < 3; ++n) acc[m][n] = (f32x4){0.f, 0.f, 0.f, 0.f};
#pragma unroll
  for (int kk = 0; kk < 8; ++kk) {
    long long a[3], bb[3];
#pragma unroll
    for (int m = 0; m < 3; ++m) {
      int r = m * 16 + lr;
      int off = r * 256 + ((((kk << 1) | (lg >> 1)) ^ (r & 15)) << 4) + ((lg & 1) << 3);
      a[m] = *(const long long*)&A8[off];
      bb[m] = *(const long long*)&B8[off];
    }
#pragma unroll
    for (int m = 0; m < 3; ++m)
#pragma unroll
      for (int n = 0; n < 3; ++n)
        acc[m][n] = __builtin_amdgcn_mfma_f32_16x16x32_fp8_fp8(a[m], bb[n], acc[m][n], 0, 0, 0);
  }
  const float SC = 6.103515625e-05f;
#pragma unroll
  for (int n = 0; n < 3; ++n) {
    int i = n * 16 + lr;
    int sv = src[b * 48 + i];
    float bvv = bv[sv];
#pragma unroll
    for (int m = 0; m < 3; ++m) {
#pragma unroll
      for (int g = 0; g < 4; ++g) {
        int j = m * 16 + lg * 4 + g;
        float val = __expf(acc[m][n][g] * SC + bvv) / dsum[rbase + j];
        em[b * 4608 + (half * 48 + j) * 48 + i] = val;
      }
    }
  }
}

// ---- fused HMM forward/backward: blocks 0..31 forward(batch), 32..63 backward(batch) ----
__global__ __launch_bounds__(192) void k_fb(const float* __restrict__ Atr, const float* __restrict__ pi,
                                            const float* __restrict__ em, float* __restrict__ alph,
                                            float* __restrict__ betas, float* __restrict__ out1) {
  __shared__ float A_st[96 * 97];                 // [s][t] padded
  __shared__ float em_lds[48 * 97];               // [i][s] padded
  __shared__ __align__(16) float vec_lds[96];     // acur (fwd) / eb (bwd)
  __shared__ float red[3];
  int t = threadIdx.x;
  int bid = blockIdx.x;
  int b = bid & 31;
  int role = bid >> 5;
  int col = t >> 1, half = t & 1;
  int base = b * 4608;

  for (int idx = t; idx < 96 * 96; idx += 192) {
    int s = idx / 96, tt = idx % 96;
    A_st[s * 97 + tt] = Atr[b * 9216 + idx];
  }
  for (int idx = t; idx < 96 * 48; idx += 192) {
    int s = idx / 48, i = idx % 48;
    em_lds[i * 97 + s] = em[base + idx];
  }
  __syncthreads();

  float Areg[48];
  if (role == 0) {
#pragma unroll
    for (int ss = 0; ss < 48; ++ss) Areg[ss] = A_st[(half * 48 + ss) * 97 + col];

    float llsum;
    {
      float v = pi[b * 96 + col] * em_lds[0 * 97 + col];
      float ws = half ? 0.f : v;
      ws = wave_sum(ws);
      if ((t & 63) == 0) red[t >> 6] = ws;
      __syncthreads();
      float c = red[0] + red[1] + red[2];
      float a = v / c;
      if (!half) {
        vec_lds[col] = a;
        alph[base + col] = a;
      }
      llsum = logf(c);
      __syncthreads();
    }
    for (int i = 1; i < 48; ++i) {
      float p = 0.f;
      const float4* ap = (const float4*)&vec_lds[half * 48];
#pragma unroll
      for (int q = 0; q < 12; ++q) {
        float4 av = ap[q];
        p += av.x * Areg[4 * q] + av.y * Areg[4 * q + 1] + av.z * Areg[4 * q + 2] + av.w * Areg[4 * q + 3];
      }
      p += __shfl_xor(p, 1);
      float an = p * em_lds[i * 97 + col];
      float ws = half ? 0.f : an;
      ws = wave_sum(ws);
      if ((t & 63) == 0) red[t >> 6] = ws;
      __syncthreads();
      float c = red[0] + red[1] + red[2];
      float a = an / c;
      if (!half) {
        vec_lds[col] = a;
        alph[base + i * 96 + col] = a;
      }
      llsum += logf(c);
      __syncthreads();
    }
    if (t == 0) out1[b] = -llsum;
  } else {
#pragma unroll
    for (int tt = 0; tt < 48; ++tt) Areg[tt] = A_st[col * 97 + half * 48 + tt];

    if (!half) {
      betas[base + 47 * 96 + col] = 1.0f;
      vec_lds[col] = em_lds[47 * 97 + col];
    }
    __syncthreads();
    for (int i = 46; i >= 0; --i) {
      float p = 0.f;
      const float4* ep = (const float4*)&vec_lds[half * 48];
#pragma unroll
      for (int q = 0; q < 12; ++q) {
        float4 ev = ep[q];
        p += ev.x * Areg[4 * q] + ev.y * Areg[4 * q + 1] + ev.z * Areg[4 * q + 2] + ev.w * Areg[4 * q + 3];
      }
      p += __shfl_xor(p, 1);
      float ws = half ? 0.f : p;
      ws = wave_sum(ws);
      if ((t & 63) == 0) red[t >> 6] = ws;
      __syncthreads();
      float c = red[0] + red[1] + red[2];
      float bt = p / c;
      if (!half) {
        betas[base + i * 96 + col] = bt;
        vec_lds[col] = em_lds[i * 97 + col] * bt;
      }
      __syncthreads();
    }
  }
}

// ---- gamma = alpha*beta, renormalized per (b,i); write transposed [b][s][i] ----
__global__ __launch_bounds__(128) void k_gamma(const float* __restrict__ alph,
                                               const float* __restrict__ betas,
                                               float* __restrict__ out0) {
  __shared__ float red[2];
  int b = blockIdx.x, i = blockIdx.y;
  int t = threadIdx.x;
  float g = 0.f;
  if (t < 96) g = alph[b * 4608 + i * 96 + t] * betas[b * 4608 + i * 96 + t];
  float ws = wave_sum(g);
  if ((t & 63) == 0) red[t >> 6] = ws;
  __syncthreads();
  float c = red[0] + red[1];
  if (t < 96) out0[b * 4608 + t * 48 + i] = g / c;
}

extern "C" void kernel_launch(void* const* d_in, const int* in_sizes, int n_in,
                              void* d_out, int out_size, void* d_ws, size_t ws_size,
                              hipStream_t stream) {
  const float* emb = (const float*)d_in[0];
  const float* Wb  = (const float*)d_in[1];
  const float* Wh  = (const float*)d_in[2];
  const float* bh  = (const float*)d_in[3];
  const float* Wv  = (const float*)d_in[4];
  const float* bv  = (const float*)d_in[5];
  const float* Atr = (const float*)d_in[6];
  const float* pi  = (const float*)d_in[7];
  const int* tc    = (const int*)d_in[8];
  const int* tcn   = (const int*)d_in[9];
  const int* src   = (const int*)d_in[10];

  float* out0 = (float*)d_out;
  float* out1 = out0 + NB * NS * NI;

  char* ws = (char*)d_ws;
  unsigned char* wv8 = (unsigned char*)(ws);                    //  8,192,000 B
  unsigned char* hb8 = (unsigned char*)(ws + 8192000);          //    786,432 B
  float* dpart       = (float*)(ws + 8978432);                  //  3,072,000 B
  float* betas       = (float*)(ws + 8978432);                  //  reuse: dpart dead after k_reduce
  float* dsum        = (float*)(ws + 12050432);                 //     12,288 B
  float* em          = (float*)(ws + 12062720);                 //    589,824 B
  float* alph        = (float*)(ws + 12652544);                 //    589,824 B

  k_transpose<<<dim3(500, 4), 256, 0, stream>>>(Wv, wv8);
  k_bridge<<<192, 256, 0, stream>>>(emb, Wb, Wh, bh, tc, tcn, hb8);
  k_denom<<<6000, 256, 0, stream>>>(hb8, wv8, bv, dpart);
  k_reduce<<<12, 256, 0, stream>>>(dpart, dsum);
  k_emis<<<64, 64, 0, stream>>>(hb8, wv8, bv, dsum, src, em);
  k_fb<<<64, 192, 0, stream>>>(Atr, pi, em, alph, betas, out1);
  k_gamma<<<dim3(32, 48), 128, 0, stream>>>(alph, betas, out0);
}

// Round 5
// 172.070 us; speedup vs baseline: 1.6365x; 1.1942x over previous
//
#include <hip/hip_runtime.h>
#include <hip/hip_bf16.h>

#define NB 32
#define NJ 48
#define NI 48
#define NCTX 5
#define NE 128
#define NH 256
#define NVS 32000
#define NS 96
#define NR 3072   // 2*B*J rows

typedef __attribute__((ext_vector_type(8))) short bf16x8;
typedef __attribute__((ext_vector_type(4))) float f32x4;

__device__ __forceinline__ unsigned short f2b(float f) {
  __hip_bfloat16 h = __float2bfloat16(f);
  return *reinterpret_cast<unsigned short*>(&h);
}
__device__ __forceinline__ float wave_sum(float v) {
  v += __shfl_xor(v, 1);
  v += __shfl_xor(v, 2);
  v += __shfl_xor(v, 4);
  v += __shfl_xor(v, 8);
  v += __shfl_xor(v, 16);
  v += __shfl_xor(v, 32);
  return v;
}
__device__ __forceinline__ void gload_lds16(const void* g, void* l) {
  __builtin_amdgcn_global_load_lds(
      (const __attribute__((address_space(1))) void*)g,
      (__attribute__((address_space(3))) void*)l, 16, 0, 0);
}

// ---- W_vocab [256][32000] f32 -> Wv8 [32000][256] fp8 e4m3, scaled x64 ----
__global__ __launch_bounds__(256) void k_transpose(const float* __restrict__ Wv,
                                                   unsigned char* __restrict__ Wv8) {
  __shared__ float tile[64][65];
  int t = threadIdx.x;
  int v0 = blockIdx.x * 64, k0 = blockIdx.y * 64;
  {
    int kr = t >> 4, vq = t & 15;
#pragma unroll
    for (int it = 0; it < 4; ++it) {
      float4 v = *(const float4*)&Wv[(k0 + kr + 16 * it) * NVS + v0 + vq * 4];
      tile[kr + 16 * it][vq * 4 + 0] = v.x;
      tile[kr + 16 * it][vq * 4 + 1] = v.y;
      tile[kr + 16 * it][vq * 4 + 2] = v.z;
      tile[kr + 16 * it][vq * 4 + 3] = v.w;
    }
  }
  __syncthreads();
  {
    int vl = t >> 2, kq = t & 3;
    unsigned int q8[4];
#pragma unroll
    for (int d = 0; d < 4; ++d) {
      float f0 = tile[kq * 16 + d * 4 + 0][vl] * 64.0f;
      float f1 = tile[kq * 16 + d * 4 + 1][vl] * 64.0f;
      float f2 = tile[kq * 16 + d * 4 + 2][vl] * 64.0f;
      float f3 = tile[kq * 16 + d * 4 + 3][vl] * 64.0f;
      int w = __builtin_amdgcn_cvt_pk_fp8_f32(f0, f1, 0, false);
      w = __builtin_amdgcn_cvt_pk_fp8_f32(f2, f3, w, true);
      q8[d] = (unsigned int)w;
    }
    *(uint4*)&Wv8[(v0 + vl) * 256 + k0 + kq * 16] = *(uint4*)q8;
  }
}

// ---- generic transpose-convert: src [R][C] f32 -> dst [C][R] bf16 ----
__global__ __launch_bounds__(256) void k_t2b(const float* __restrict__ src,
                                             unsigned short* __restrict__ dst,
                                             int R, int C) {
  __shared__ float tile[64][65];
  int t = threadIdx.x;
  int r0 = blockIdx.x * 64, c0 = blockIdx.y * 64;
  {
    int rr = t >> 4, cq = t & 15;
#pragma unroll
    for (int it = 0; it < 4; ++it) {
      float4 v = *(const float4*)&src[(r0 + rr + 16 * it) * C + c0 + cq * 4];
      tile[rr + 16 * it][cq * 4 + 0] = v.x;
      tile[rr + 16 * it][cq * 4 + 1] = v.y;
      tile[rr + 16 * it][cq * 4 + 2] = v.z;
      tile[rr + 16 * it][cq * 4 + 3] = v.w;
    }
  }
  __syncthreads();
  {
    int cc = t >> 2, rq = t & 3;
    unsigned short pk[16];
#pragma unroll
    for (int q = 0; q < 16; ++q) pk[q] = f2b(tile[rq * 16 + q][cc]);
    *(uint4*)&dst[(c0 + cc) * R + r0 + rq * 16] = *(uint4*)&pk[0];
    *(uint4*)&dst[(c0 + cc) * R + r0 + rq * 16 + 8] = *(uint4*)&pk[8];
  }
}

// ---- GEMM1: xb[3072][128] bf16 = gather(emb) @ Wb ; MFMA, 64-row tiles ----
__global__ __launch_bounds__(256) void k_xb(const float* __restrict__ emb,
                                            const unsigned short* __restrict__ Wbt,
                                            const int* __restrict__ tc, const int* __restrict__ tcn,
                                            unsigned short* __restrict__ xb) {
  __shared__ unsigned short Ax[64 * 72];
  __shared__ unsigned short Bw[128 * 72];
  __shared__ unsigned short xout[64 * 136];
  int t = threadIdx.x;
  int r0 = blockIdx.x * 64;
  int wave = t >> 6, lane = t & 63;
  int wm = wave >> 1, wn = wave & 1;
  int lg = lane >> 4, lr = lane & 15;
  // A staging mapping: 4 threads per row, 16 cols each
  int arow = t >> 2, aseg = t & 3;
  int r = r0 + arow;
  int half = r / 1536, rem = r % 1536, bb = rem / 48, jj = rem % 48;
  const int* ids = half ? tcn : tc;
  // B staging mapping: 2 threads per row, 32 cols each
  int brow = t >> 1, bseg = t & 1;

  f32x4 acc[2][4];
#pragma unroll
  for (int m = 0; m < 2; ++m)
#pragma unroll
    for (int n = 0; n < 4; ++n) acc[m][n] = (f32x4){0.f, 0.f, 0.f, 0.f};

  for (int step = 0; step < 10; ++step) {
    int k0 = step * 64;
    int p = k0 >> 7;            // embedding part (64 | 128 so no straddle)
    int e0 = k0 & 127;
    // stage A: gather + cvt
    {
      int id = ids[bb * 240 + jj * 5 + p];
      const float4* er = (const float4*)&emb[id * 128 + e0 + aseg * 16];
      unsigned short pk[16];
#pragma unroll
      for (int q = 0; q < 4; ++q) {
        float4 v = er[q];
        pk[q * 4 + 0] = f2b(v.x);
        pk[q * 4 + 1] = f2b(v.y);
        pk[q * 4 + 2] = f2b(v.z);
        pk[q * 4 + 3] = f2b(v.w);
      }
      *(uint4*)&Ax[arow * 72 + aseg * 16] = *(uint4*)&pk[0];
      *(uint4*)&Ax[arow * 72 + aseg * 16 + 8] = *(uint4*)&pk[8];
    }
    // stage B: Wbt rows (all 128 outs), cols k0..k0+63
    {
      const uint4* wp = (const uint4*)&Wbt[brow * 640 + k0 + bseg * 32];
      uint4* dp = (uint4*)&Bw[brow * 72 + bseg * 32];
      uint4 w0 = wp[0], w1 = wp[1], w2 = wp[2], w3 = wp[3];
      dp[0] = w0; dp[1] = w1; dp[2] = w2; dp[3] = w3;
    }
    __syncthreads();
#pragma unroll
    for (int kk = 0; kk < 2; ++kk) {
      bf16x8 a[2], b[4];
#pragma unroll
      for (int m = 0; m < 2; ++m)
        a[m] = *(const bf16x8*)&Ax[(wm * 32 + m * 16 + lr) * 72 + kk * 32 + lg * 8];
#pragma unroll
      for (int n = 0; n < 4; ++n)
        b[n] = *(const bf16x8*)&Bw[(wn * 64 + n * 16 + lr) * 72 + kk * 32 + lg * 8];
#pragma unroll
      for (int m = 0; m < 2; ++m)
#pragma unroll
        for (int n = 0; n < 4; ++n)
          acc[m][n] = __builtin_amdgcn_mfma_f32_16x16x32_bf16(a[m], b[n], acc[m][n], 0, 0, 0);
    }
    __syncthreads();
  }
  // epilogue: stage bf16 to LDS, then coalesced store
#pragma unroll
  for (int m = 0; m < 2; ++m)
#pragma unroll
    for (int n = 0; n < 4; ++n)
#pragma unroll
      for (int g = 0; g < 4; ++g)
        xout[(wm * 32 + m * 16 + lg * 4 + g) * 136 + wn * 64 + n * 16 + lr] = f2b(acc[m][n][g]);
  __syncthreads();
  {
    int orow = t >> 2, os = t & 3;
#pragma unroll
    for (int i = 0; i < 4; ++i)
      ((uint4*)&xb[(r0 + orow) * 128])[os * 4 + i] = *(uint4*)&xout[orow * 136 + (os * 4 + i) * 8];
  }
}

// ---- GEMM2: h = tanh(xb @ Wh + bh) -> fp8 hb8 [3072][256] ; 128x128x128 ----
__global__ __launch_bounds__(256) void k_h(const unsigned short* __restrict__ xb,
                                           const unsigned short* __restrict__ Wht,
                                           const float* __restrict__ bh,
                                           unsigned char* __restrict__ hb8) {
  __shared__ char smem[69632];
  unsigned short* Asm = (unsigned short*)smem;            // [128][136]
  unsigned short* Bsm = (unsigned short*)(smem + 34816);  // [128][136]
  unsigned char* o8 = (unsigned char*)smem;               // reuse: [128][144]
  int t = threadIdx.x;
  int r0 = blockIdx.x * 128, n0 = blockIdx.y * 128;
  int wave = t >> 6, lane = t & 63;
  int wm = wave >> 1, wn = wave & 1;
  int lg = lane >> 4, lr = lane & 15;
  {
    int row = t >> 1, seg = t & 1;
#pragma unroll
    for (int i = 0; i < 8; ++i) {
      *(uint4*)&Asm[row * 136 + seg * 64 + i * 8] = *(const uint4*)&xb[(r0 + row) * 128 + seg * 64 + i * 8];
      *(uint4*)&Bsm[row * 136 + seg * 64 + i * 8] = *(const uint4*)&Wht[(n0 + row) * 128 + seg * 64 + i * 8];
    }
  }
  __syncthreads();
  f32x4 acc[4][4];
#pragma unroll
  for (int m = 0; m < 4; ++m)
#pragma unroll
    for (int n = 0; n < 4; ++n) acc[m][n] = (f32x4){0.f, 0.f, 0.f, 0.f};
#pragma unroll
  for (int kk = 0; kk < 4; ++kk) {
    bf16x8 a[4], b[4];
#pragma unroll
    for (int m = 0; m < 4; ++m)
      a[m] = *(const bf16x8*)&Asm[(wm * 64 + m * 16 + lr) * 136 + kk * 32 + lg * 8];
#pragma unroll
    for (int n = 0; n < 4; ++n)
      b[n] = *(const bf16x8*)&Bsm[(wn * 64 + n * 16 + lr) * 136 + kk * 32 + lg * 8];
#pragma unroll
    for (int m = 0; m < 4; ++m)
#pragma unroll
      for (int n = 0; n < 4; ++n)
        acc[m][n] = __builtin_amdgcn_mfma_f32_16x16x32_bf16(a[m], b[n], acc[m][n], 0, 0, 0);
  }
  __syncthreads();  // A/B dead; reuse smem as o8
#pragma unroll
  for (int n = 0; n < 4; ++n) {
    int cl = wn * 64 + n * 16 + lr;
    float bvv = bh[n0 + cl];
#pragma unroll
    for (int m = 0; m < 4; ++m) {
#pragma unroll
      for (int g = 0; g < 4; ++g) {
        int rl = wm * 64 + m * 16 + lg * 4 + g;
        float hv = tanhf(acc[m][n][g] + bvv);
        int p8 = __builtin_amdgcn_cvt_pk_fp8_f32(hv * 256.0f, 0.0f, 0, false);
        o8[rl * 144 + cl] = (unsigned char)(p8 & 0xFF);
      }
    }
  }
  __syncthreads();
  {
    int row = t >> 1, seg = t & 1;
#pragma unroll
    for (int i = 0; i < 4; ++i)
      *(uint4*)&hb8[(r0 + row) * 256 + n0 + seg * 64 + i * 16] = *(uint4*)&o8[row * 144 + seg * 64 + i * 16];
  }
}

// ---- denominator GEMM: rowsum of exp((h8 @ Wv8)*2^-14 + bv), fp8 MFMA, 128x128 ----
__global__ __launch_bounds__(256) void k_denom(const unsigned char* __restrict__ hb8,
                                               const unsigned char* __restrict__ Wv8,
                                               const float* __restrict__ bv,
                                               float* __restrict__ dpart) {
  __shared__ unsigned char Asm[128 * 64];
  __shared__ unsigned char Bsm[128 * 64];
  __shared__ float red2[2][128];
  int t = threadIdx.x;
  int bid = blockIdx.x;                 // 0..5999 ; 6000 = 8 * 750
  int xcd = bid & 7;
  int pos = bid >> 3;
  int tile = xcd * 750 + pos;
  int vt = tile / 24, rt = tile % 24;
  int v0 = vt * 128, r0 = rt * 128;
  int wave = t >> 6, lane = t & 63;
  int wm = wave >> 1, wn = wave & 1;
  int lg = lane >> 4, lr = lane & 15;
  int srow = lane >> 2;
  int sseg = (lane & 3) ^ (srow & 3);

  f32x4 acc[4][4];
#pragma unroll
  for (int m = 0; m < 4; ++m)
#pragma unroll
    for (int n = 0; n < 4; ++n) acc[m][n] = (f32x4){0.f, 0.f, 0.f, 0.f};

  for (int k0 = 0; k0 < 256; k0 += 64) {
#pragma unroll
    for (int c = 0; c < 2; ++c) {
      int inst = wave * 2 + c;
      int row = inst * 16 + srow;
      gload_lds16(&hb8[(r0 + row) * 256 + k0 + sseg * 16], &Asm[inst * 1024]);
      gload_lds16(&Wv8[(v0 + row) * 256 + k0 + sseg * 16], &Bsm[inst * 1024]);
    }
    __syncthreads();
#pragma unroll
    for (int kk = 0; kk < 2; ++kk) {
      long long a[4], b[4];
#pragma unroll
      for (int m = 0; m < 4; ++m) {
        int rr = wm * 64 + m * 16 + lr;
        int off = rr * 64 + ((((kk << 1) | (lg >> 1)) ^ (rr & 3)) << 4) + ((lg & 1) << 3);
        a[m] = *(const long long*)&Asm[off];
      }
#pragma unroll
      for (int n = 0; n < 4; ++n) {
        int rr = wn * 64 + n * 16 + lr;
        int off = rr * 64 + ((((kk << 1) | (lg >> 1)) ^ (rr & 3)) << 4) + ((lg & 1) << 3);
        b[n] = *(const long long*)&Bsm[off];
      }
#pragma unroll
      for (int m = 0; m < 4; ++m)
#pragma unroll
        for (int n = 0; n < 4; ++n)
          acc[m][n] = __builtin_amdgcn_mfma_f32_16x16x32_fp8_fp8(a[m], b[n], acc[m][n], 0, 0, 0);
    }
    __syncthreads();
  }

  const float SC = 6.103515625e-05f;  // 2^-14 (h x256, w x64)
  float rs[4][4];
#pragma unroll
  for (int m = 0; m < 4; ++m)
#pragma unroll
    for (int g = 0; g < 4; ++g) rs[m][g] = 0.f;
#pragma unroll
  for (int m = 0; m < 4; ++m) {
#pragma unroll
    for (int n = 0; n < 4; ++n) {
      float bvv = bv[v0 + wn * 64 + n * 16 + lr];
#pragma unroll
      for (int g = 0; g < 4; ++g) rs[m][g] += __expf(acc[m][n][g] * SC + bvv);
    }
  }
#pragma unroll
  for (int m = 0; m < 4; ++m)
#pragma unroll
    for (int g = 0; g < 4; ++g) {
      float v = rs[m][g];
      v += __shfl_xor(v, 1);
      v += __shfl_xor(v, 2);
      v += __shfl_xor(v, 4);
      v += __shfl_xor(v, 8);
      rs[m][g] = v;
    }
  if (lr == 0) {
#pragma unroll
    for (int m = 0; m < 4; ++m)
#pragma unroll
      for (int g = 0; g < 4; ++g)
        red2[wn][wm * 64 + m * 16 + lg * 4 + g] = rs[m][g];
  }
  __syncthreads();
  if (t < 128) dpart[vt * NR + r0 + t] = red2[0][t] + red2[1][t];
}

// ---- reduce partial denominators ----
__global__ void k_reduce(const float* __restrict__ dpart, float* __restrict__ dsum) {
  int r = blockIdx.x * 256 + threadIdx.x;
  float s = 0.f;
  for (int vt = 0; vt < 250; ++vt) s += dpart[vt * NR + r];
  dsum[r] = s;
}

// ---- emission numerators via fp8 MFMA: one 64-thread block per (b,half) ----
__global__ __launch_bounds__(64) void k_emis(const unsigned char* __restrict__ hb8,
                                             const unsigned char* __restrict__ Wv8,
                                             const float* __restrict__ bv,
                                             const float* __restrict__ dsum,
                                             const int* __restrict__ src,
                                             float* __restrict__ em) {
  __shared__ unsigned char A8[48 * 256];
  __shared__ unsigned char B8[48 * 256];
  int t = threadIdx.x;
  int bh = blockIdx.x;
  int b = bh & 31, half = bh >> 5;
  int row4 = t >> 4, seg = t & 15;
  int rbase = half * 1536 + b * 48;
#pragma unroll
  for (int c = 0; c < 12; ++c) {
    int row = c * 4 + row4;
    int gseg = seg ^ (row & 15);
    gload_lds16(&hb8[(rbase + row) * 256 + gseg * 16], &A8[c * 1024]);
    int sv = src[b * 48 + row];
    gload_lds16(&Wv8[sv * 256 + gseg * 16], &B8[c * 1024]);
  }
  __syncthreads();
  int lg = t >> 4, lr = t & 15;
  f32x4 acc[3][3];
#pragma unroll
  for (int m = 0; m < 3; ++m)
#pragma unroll
    for (int n = 0; n < 3; ++n) acc[m][n] = (f32x4){0.f, 0.f, 0.f, 0.f};
#pragma unroll
  for (int kk = 0; kk < 8; ++kk) {
    long long a[3], bb[3];
#pragma unroll
    for (int m = 0; m < 3; ++m) {
      int rr = m * 16 + lr;
      int off = rr * 256 + ((((kk << 1) | (lg >> 1)) ^ (rr & 15)) << 4) + ((lg & 1) << 3);
      a[m] = *(const long long*)&A8[off];
      bb[m] = *(const long long*)&B8[off];
    }
#pragma unroll
    for (int m = 0; m < 3; ++m)
#pragma unroll
      for (int n = 0; n < 3; ++n)
        acc[m][n] = __builtin_amdgcn_mfma_f32_16x16x32_fp8_fp8(a[m], bb[n], acc[m][n], 0, 0, 0);
  }
  const float SC = 6.103515625e-05f;
#pragma unroll
  for (int n = 0; n < 3; ++n) {
    int i = n * 16 + lr;
    int sv = src[b * 48 + i];
    float bvv = bv[sv];
#pragma unroll
    for (int m = 0; m < 3; ++m) {
#pragma unroll
      for (int g = 0; g < 4; ++g) {
        int j = m * 16 + lg * 4 + g;
        float val = __expf(acc[m][n][g] * SC + bvv) / dsum[rbase + j];
        em[b * 4608 + (half * 48 + j) * 48 + i] = val;
      }
    }
  }
}

// ---- fused HMM forward/backward: blocks 0..31 forward(batch), 32..63 backward(batch) ----
__global__ __launch_bounds__(192) void k_fb(const float* __restrict__ Atr, const float* __restrict__ pi,
                                            const float* __restrict__ em, float* __restrict__ alph,
                                            float* __restrict__ betas, float* __restrict__ out1) {
  __shared__ float A_st[96 * 97];
  __shared__ float em_lds[48 * 97];
  __shared__ __align__(16) float vec_lds[96];
  __shared__ float red[3];
  int t = threadIdx.x;
  int bid = blockIdx.x;
  int b = bid & 31;
  int role = bid >> 5;
  int col = t >> 1, half = t & 1;
  int base = b * 4608;

  for (int idx = t; idx < 96 * 96; idx += 192) {
    int s = idx / 96, tt = idx % 96;
    A_st[s * 97 + tt] = Atr[b * 9216 + idx];
  }
  for (int idx = t; idx < 96 * 48; idx += 192) {
    int s = idx / 48, i = idx % 48;
    em_lds[i * 97 + s] = em[base + idx];
  }
  __syncthreads();

  float Areg[48];
  if (role == 0) {
#pragma unroll
    for (int ss = 0; ss < 48; ++ss) Areg[ss] = A_st[(half * 48 + ss) * 97 + col];

    float llsum;
    {
      float v = pi[b * 96 + col] * em_lds[0 * 97 + col];
      float ws = half ? 0.f : v;
      ws = wave_sum(ws);
      if ((t & 63) == 0) red[t >> 6] = ws;
      __syncthreads();
      float c = red[0] + red[1] + red[2];
      float a = v / c;
      if (!half) {
        vec_lds[col] = a;
        alph[base + col] = a;
      }
      llsum = logf(c);
      __syncthreads();
    }
    for (int i = 1; i < 48; ++i) {
      float p = 0.f;
      const float4* ap = (const float4*)&vec_lds[half * 48];
#pragma unroll
      for (int q = 0; q < 12; ++q) {
        float4 av = ap[q];
        p += av.x * Areg[4 * q] + av.y * Areg[4 * q + 1] + av.z * Areg[4 * q + 2] + av.w * Areg[4 * q + 3];
      }
      p += __shfl_xor(p, 1);
      float an = p * em_lds[i * 97 + col];
      float ws = half ? 0.f : an;
      ws = wave_sum(ws);
      if ((t & 63) == 0) red[t >> 6] = ws;
      __syncthreads();
      float c = red[0] + red[1] + red[2];
      float a = an / c;
      if (!half) {
        vec_lds[col] = a;
        alph[base + i * 96 + col] = a;
      }
      llsum += logf(c);
      __syncthreads();
    }
    if (t == 0) out1[b] = -llsum;
  } else {
#pragma unroll
    for (int tt = 0; tt < 48; ++tt) Areg[tt] = A_st[col * 97 + half * 48 + tt];

    if (!half) {
      betas[base + 47 * 96 + col] = 1.0f;
      vec_lds[col] = em_lds[47 * 97 + col];
    }
    __syncthreads();
    for (int i = 46; i >= 0; --i) {
      float p = 0.f;
      const float4* ep = (const float4*)&vec_lds[half * 48];
#pragma unroll
      for (int q = 0; q < 12; ++q) {
        float4 ev = ep[q];
        p += ev.x * Areg[4 * q] + ev.y * Areg[4 * q + 1] + ev.z * Areg[4 * q + 2] + ev.w * Areg[4 * q + 3];
      }
      p += __shfl_xor(p, 1);
      float ws = half ? 0.f : p;
      ws = wave_sum(ws);
      if ((t & 63) == 0) red[t >> 6] = ws;
      __syncthreads();
      float c = red[0] + red[1] + red[2];
      float bt = p / c;
      if (!half) {
        betas[base + i * 96 + col] = bt;
        vec_lds[col] = em_lds[i * 97 + col] * bt;
      }
      __syncthreads();
    }
  }
}

// ---- gamma = alpha*beta, renormalized per (b,i); write transposed [b][s][i] ----
__global__ __launch_bounds__(128) void k_gamma(const float* __restrict__ alph,
                                               const float* __restrict__ betas,
                                               float* __restrict__ out0) {
  __shared__ float red[2];
  int b = blockIdx.x, i = blockIdx.y;
  int t = threadIdx.x;
  float g = 0.f;
  if (t < 96) g = alph[b * 4608 + i * 96 + t] * betas[b * 4608 + i * 96 + t];
  float ws = wave_sum(g);
  if ((t & 63) == 0) red[t >> 6] = ws;
  __syncthreads();
  float c = red[0] + red[1];
  if (t < 96) out0[b * 4608 + t * 48 + i] = g / c;
}

extern "C" void kernel_launch(void* const* d_in, const int* in_sizes, int n_in,
                              void* d_out, int out_size, void* d_ws, size_t ws_size,
                              hipStream_t stream) {
  const float* emb = (const float*)d_in[0];
  const float* Wb  = (const float*)d_in[1];
  const float* Wh  = (const float*)d_in[2];
  const float* bh  = (const float*)d_in[3];
  const float* Wv  = (const float*)d_in[4];
  const float* bv  = (const float*)d_in[5];
  const float* Atr = (const float*)d_in[6];
  const float* pi  = (const float*)d_in[7];
  const int* tc    = (const int*)d_in[8];
  const int* tcn   = (const int*)d_in[9];
  const int* src   = (const int*)d_in[10];

  float* out0 = (float*)d_out;
  float* out1 = out0 + NB * NS * NI;

  char* ws = (char*)d_ws;
  unsigned char* wv8 = (unsigned char*)(ws);                    //  8,192,000 B
  unsigned char* hb8 = (unsigned char*)(ws + 8192000);          //    786,432 B
  float* dpart       = (float*)(ws + 8978432);                  //  3,072,000 B
  float* betas       = (float*)(ws + 8978432);                  //  reuse: dpart dead after k_reduce
  float* dsum        = (float*)(ws + 12050432);                 //     12,288 B
  float* em          = (float*)(ws + 12062720);                 //    589,824 B
  float* alph        = (float*)(ws + 12652544);                 //    589,824 B
  unsigned short* wbt = (unsigned short*)(ws + 13242368);       //    163,840 B
  unsigned short* wht = (unsigned short*)(ws + 13406208);       //     65,536 B
  unsigned short* xb  = (unsigned short*)(ws + 13471744);       //    786,432 B

  k_transpose<<<dim3(500, 4), 256, 0, stream>>>(Wv, wv8);
  k_t2b<<<dim3(10, 2), 256, 0, stream>>>(Wb, wbt, 640, 128);
  k_t2b<<<dim3(2, 4), 256, 0, stream>>>(Wh, wht, 128, 256);
  k_xb<<<48, 256, 0, stream>>>(emb, wbt, tc, tcn, xb);
  k_h<<<dim3(24, 2), 256, 0, stream>>>(xb, wht, bh, hb8);
  k_denom<<<6000, 256, 0, stream>>>(hb8, wv8, bv, dpart);
  k_reduce<<<12, 256, 0, stream>>>(dpart, dsum);
  k_emis<<<64, 64, 0, stream>>>(hb8, wv8, bv, dsum, src, em);
  k_fb<<<64, 192, 0, stream>>>(Atr, pi, em, alph, betas, out1);
  k_gamma<<<dim3(32, 48), 128, 0, stream>>>(alph, betas, out0);
}

// Round 6
// 161.566 us; speedup vs baseline: 1.7429x; 1.0650x over previous
//
#include <hip/hip_runtime.h>
#include <hip/hip_bf16.h>

#define NB 32
#define NJ 48
#define NI 48
#define NCTX 5
#define NE 128
#define NH 256
#define NVS 32000
#define NS 96
#define NR 3072   // 2*B*J rows

typedef __attribute__((ext_vector_type(8))) short bf16x8;
typedef __attribute__((ext_vector_type(4))) float f32x4;

__device__ __forceinline__ unsigned short f2b(float f) {
  __hip_bfloat16 h = __float2bfloat16(f);
  return *reinterpret_cast<unsigned short*>(&h);
}
__device__ __forceinline__ float wave_sum(float v) {
  v += __shfl_xor(v, 1);
  v += __shfl_xor(v, 2);
  v += __shfl_xor(v, 4);
  v += __shfl_xor(v, 8);
  v += __shfl_xor(v, 16);
  v += __shfl_xor(v, 32);
  return v;
}
__device__ __forceinline__ void gload_lds16(const void* g, void* l) {
  __builtin_amdgcn_global_load_lds(
      (const __attribute__((address_space(1))) void*)g,
      (__attribute__((address_space(3))) void*)l, 16, 0, 0);
}

// ---- W_vocab [256][32000] f32 -> Wv8 [32000][256] fp8 e4m3, scaled x64 ----
__global__ __launch_bounds__(256) void k_transpose(const float* __restrict__ Wv,
                                                   unsigned char* __restrict__ Wv8) {
  __shared__ float tile[64][65];
  int t = threadIdx.x;
  int v0 = blockIdx.x * 64, k0 = blockIdx.y * 64;
  {
    int kr = t >> 4, vq = t & 15;
#pragma unroll
    for (int it = 0; it < 4; ++it) {
      float4 v = *(const float4*)&Wv[(k0 + kr + 16 * it) * NVS + v0 + vq * 4];
      tile[kr + 16 * it][vq * 4 + 0] = v.x;
      tile[kr + 16 * it][vq * 4 + 1] = v.y;
      tile[kr + 16 * it][vq * 4 + 2] = v.z;
      tile[kr + 16 * it][vq * 4 + 3] = v.w;
    }
  }
  __syncthreads();
  {
    int vl = t >> 2, kq = t & 3;
    unsigned int q8[4];
#pragma unroll
    for (int d = 0; d < 4; ++d) {
      float f0 = tile[kq * 16 + d * 4 + 0][vl] * 64.0f;
      float f1 = tile[kq * 16 + d * 4 + 1][vl] * 64.0f;
      float f2 = tile[kq * 16 + d * 4 + 2][vl] * 64.0f;
      float f3 = tile[kq * 16 + d * 4 + 3][vl] * 64.0f;
      int w = __builtin_amdgcn_cvt_pk_fp8_f32(f0, f1, 0, false);
      w = __builtin_amdgcn_cvt_pk_fp8_f32(f2, f3, w, true);
      q8[d] = (unsigned int)w;
    }
    *(uint4*)&Wv8[(v0 + vl) * 256 + k0 + kq * 16] = *(uint4*)q8;
  }
}

// ---- generic transpose-convert: src [R][C] f32 -> dst [C][R] bf16 ----
__global__ __launch_bounds__(256) void k_t2b(const float* __restrict__ src,
                                             unsigned short* __restrict__ dst,
                                             int R, int C) {
  __shared__ float tile[64][65];
  int t = threadIdx.x;
  int r0 = blockIdx.x * 64, c0 = blockIdx.y * 64;
  {
    int rr = t >> 4, cq = t & 15;
#pragma unroll
    for (int it = 0; it < 4; ++it) {
      float4 v = *(const float4*)&src[(r0 + rr + 16 * it) * C + c0 + cq * 4];
      tile[rr + 16 * it][cq * 4 + 0] = v.x;
      tile[rr + 16 * it][cq * 4 + 1] = v.y;
      tile[rr + 16 * it][cq * 4 + 2] = v.z;
      tile[rr + 16 * it][cq * 4 + 3] = v.w;
    }
  }
  __syncthreads();
  {
    int cc = t >> 2, rq = t & 3;
    unsigned short pk[16];
#pragma unroll
    for (int q = 0; q < 16; ++q) pk[q] = f2b(tile[rq * 16 + q][cc]);
    *(uint4*)&dst[(c0 + cc) * R + r0 + rq * 16] = *(uint4*)&pk[0];
    *(uint4*)&dst[(c0 + cc) * R + r0 + rq * 16 + 8] = *(uint4*)&pk[8];
  }
}

// ---- GEMM1: xb[3072][128] bf16 = gather(emb) @ Wb ; MFMA, 64-row tiles ----
__global__ __launch_bounds__(256) void k_xb(const float* __restrict__ emb,
                                            const unsigned short* __restrict__ Wbt,
                                            const int* __restrict__ tc, const int* __restrict__ tcn,
                                            unsigned short* __restrict__ xb) {
  __shared__ unsigned short Ax[64 * 72];
  __shared__ unsigned short Bw[128 * 72];
  __shared__ unsigned short xout[64 * 136];
  int t = threadIdx.x;
  int r0 = blockIdx.x * 64;
  int wave = t >> 6, lane = t & 63;
  int wm = wave >> 1, wn = wave & 1;
  int lg = lane >> 4, lr = lane & 15;
  int arow = t >> 2, aseg = t & 3;
  int r = r0 + arow;
  int half = r / 1536, rem = r % 1536, bb = rem / 48, jj = rem % 48;
  const int* ids = half ? tcn : tc;
  int brow = t >> 1, bseg = t & 1;

  f32x4 acc[2][4];
#pragma unroll
  for (int m = 0; m < 2; ++m)
#pragma unroll
    for (int n = 0; n < 4; ++n) acc[m][n] = (f32x4){0.f, 0.f, 0.f, 0.f};

  for (int step = 0; step < 10; ++step) {
    int k0 = step * 64;
    int p = k0 >> 7;
    int e0 = k0 & 127;
    {
      int id = ids[bb * 240 + jj * 5 + p];
      const float4* er = (const float4*)&emb[id * 128 + e0 + aseg * 16];
      unsigned short pk[16];
#pragma unroll
      for (int q = 0; q < 4; ++q) {
        float4 v = er[q];
        pk[q * 4 + 0] = f2b(v.x);
        pk[q * 4 + 1] = f2b(v.y);
        pk[q * 4 + 2] = f2b(v.z);
        pk[q * 4 + 3] = f2b(v.w);
      }
      *(uint4*)&Ax[arow * 72 + aseg * 16] = *(uint4*)&pk[0];
      *(uint4*)&Ax[arow * 72 + aseg * 16 + 8] = *(uint4*)&pk[8];
    }
    {
      const uint4* wp = (const uint4*)&Wbt[brow * 640 + k0 + bseg * 32];
      uint4* dp = (uint4*)&Bw[brow * 72 + bseg * 32];
      uint4 w0 = wp[0], w1 = wp[1], w2 = wp[2], w3 = wp[3];
      dp[0] = w0; dp[1] = w1; dp[2] = w2; dp[3] = w3;
    }
    __syncthreads();
#pragma unroll
    for (int kk = 0; kk < 2; ++kk) {
      bf16x8 a[2], b[4];
#pragma unroll
      for (int m = 0; m < 2; ++m)
        a[m] = *(const bf16x8*)&Ax[(wm * 32 + m * 16 + lr) * 72 + kk * 32 + lg * 8];
#pragma unroll
      for (int n = 0; n < 4; ++n)
        b[n] = *(const bf16x8*)&Bw[(wn * 64 + n * 16 + lr) * 72 + kk * 32 + lg * 8];
#pragma unroll
      for (int m = 0; m < 2; ++m)
#pragma unroll
        for (int n = 0; n < 4; ++n)
          acc[m][n] = __builtin_amdgcn_mfma_f32_16x16x32_bf16(a[m], b[n], acc[m][n], 0, 0, 0);
    }
    __syncthreads();
  }
#pragma unroll
  for (int m = 0; m < 2; ++m)
#pragma unroll
    for (int n = 0; n < 4; ++n)
#pragma unroll
      for (int g = 0; g < 4; ++g)
        xout[(wm * 32 + m * 16 + lg * 4 + g) * 136 + wn * 64 + n * 16 + lr] = f2b(acc[m][n][g]);
  __syncthreads();
  {
    int orow = t >> 2, os = t & 3;
#pragma unroll
    for (int i = 0; i < 4; ++i)
      ((uint4*)&xb[(r0 + orow) * 128])[os * 4 + i] = *(uint4*)&xout[orow * 136 + (os * 4 + i) * 8];
  }
}

// ---- GEMM2: h = tanh(xb @ Wh + bh) -> fp8 hb8 [3072][256] ; 128x128x128 ----
__global__ __launch_bounds__(256) void k_h(const unsigned short* __restrict__ xb,
                                           const unsigned short* __restrict__ Wht,
                                           const float* __restrict__ bh,
                                           unsigned char* __restrict__ hb8) {
  __shared__ char smem[69632];
  unsigned short* Asm = (unsigned short*)smem;            // [128][136]
  unsigned short* Bsm = (unsigned short*)(smem + 34816);  // [128][136]
  unsigned char* o8 = (unsigned char*)smem;               // reuse: [128][144]
  int t = threadIdx.x;
  int r0 = blockIdx.x * 128, n0 = blockIdx.y * 128;
  int wave = t >> 6, lane = t & 63;
  int wm = wave >> 1, wn = wave & 1;
  int lg = lane >> 4, lr = lane & 15;
  {
    int row = t >> 1, seg = t & 1;
#pragma unroll
    for (int i = 0; i < 8; ++i) {
      *(uint4*)&Asm[row * 136 + seg * 64 + i * 8] = *(const uint4*)&xb[(r0 + row) * 128 + seg * 64 + i * 8];
      *(uint4*)&Bsm[row * 136 + seg * 64 + i * 8] = *(const uint4*)&Wht[(n0 + row) * 128 + seg * 64 + i * 8];
    }
  }
  __syncthreads();
  f32x4 acc[4][4];
#pragma unroll
  for (int m = 0; m < 4; ++m)
#pragma unroll
    for (int n = 0; n < 4; ++n) acc[m][n] = (f32x4){0.f, 0.f, 0.f, 0.f};
#pragma unroll
  for (int kk = 0; kk < 4; ++kk) {
    bf16x8 a[4], b[4];
#pragma unroll
    for (int m = 0; m < 4; ++m)
      a[m] = *(const bf16x8*)&Asm[(wm * 64 + m * 16 + lr) * 136 + kk * 32 + lg * 8];
#pragma unroll
    for (int n = 0; n < 4; ++n)
      b[n] = *(const bf16x8*)&Bsm[(wn * 64 + n * 16 + lr) * 136 + kk * 32 + lg * 8];
#pragma unroll
    for (int m = 0; m < 4; ++m)
#pragma unroll
      for (int n = 0; n < 4; ++n)
        acc[m][n] = __builtin_amdgcn_mfma_f32_16x16x32_bf16(a[m], b[n], acc[m][n], 0, 0, 0);
  }
  __syncthreads();
#pragma unroll
  for (int n = 0; n < 4; ++n) {
    int cl = wn * 64 + n * 16 + lr;
    float bvv = bh[n0 + cl];
#pragma unroll
    for (int m = 0; m < 4; ++m) {
#pragma unroll
      for (int g = 0; g < 4; ++g) {
        int rl = wm * 64 + m * 16 + lg * 4 + g;
        float hv = tanhf(acc[m][n][g] + bvv);
        int p8 = __builtin_amdgcn_cvt_pk_fp8_f32(hv * 256.0f, 0.0f, 0, false);
        o8[rl * 144 + cl] = (unsigned char)(p8 & 0xFF);
      }
    }
  }
  __syncthreads();
  {
    int row = t >> 1, seg = t & 1;
#pragma unroll
    for (int i = 0; i < 4; ++i)
      *(uint4*)&hb8[(r0 + row) * 256 + n0 + seg * 64 + i * 16] = *(uint4*)&o8[row * 144 + seg * 64 + i * 16];
  }
}

// ---- denominator GEMM: rowsum of exp((h8 @ Wv8)*2^-14 + bv), fp8 MFMA ----
// Single-stage: full 128x256 A and B tiles staged once via global_load_lds
// (linear dest, source pre-swizzled seg^=(row&15)); zero K-loop barriers.
__global__ __launch_bounds__(256) void k_denom(const unsigned char* __restrict__ hb8,
                                               const unsigned char* __restrict__ Wv8,
                                               const float* __restrict__ bv,
                                               float* __restrict__ dpart) {
  __shared__ __align__(16) char smem[65536];
  unsigned char* Asm = (unsigned char*)smem;            // [128][256]
  unsigned char* Bsm = (unsigned char*)(smem + 32768);  // [128][256]
  float* red2 = (float*)smem;                           // overlay after MFMA: [2][128]
  int t = threadIdx.x;
  int bid = blockIdx.x;                 // 6000 = 8 * 750
  int xcd = bid & 7;
  int pos = bid >> 3;
  int tile = xcd * 750 + pos;
  int vt = tile / 24, rt = tile % 24;
  int v0 = vt * 128, r0 = rt * 128;
  int wave = t >> 6, lane = t & 63;
  int wm = wave >> 1, wn = wave & 1;
  int lg = lane >> 4, lr = lane & 15;

  // stage entire tiles: 32 chunks each (4 rows x 256B per chunk), 8+8 insts/wave
  {
    int rloc = lane >> 4;        // row within chunk
    int seg = lane & 15;
#pragma unroll
    for (int c = 0; c < 8; ++c) {
      int chunk = wave * 8 + c;                // 0..31
      int row = chunk * 4 + rloc;
      int gseg = seg ^ (row & 15);
      gload_lds16(&hb8[(r0 + row) * 256 + gseg * 16], &Asm[chunk * 1024]);
      gload_lds16(&Wv8[(v0 + row) * 256 + gseg * 16], &Bsm[chunk * 1024]);
    }
  }
  __syncthreads();

  f32x4 acc[4][4];
#pragma unroll
  for (int m = 0; m < 4; ++m)
#pragma unroll
    for (int n = 0; n < 4; ++n) acc[m][n] = (f32x4){0.f, 0.f, 0.f, 0.f};

#pragma unroll
  for (int K = 0; K < 4; ++K) {
#pragma unroll
    for (int kk = 0; kk < 2; ++kk) {
      int lseg = (K << 2) + (kk << 1) + (lg >> 1);   // logical 16B seg 0..15
      int hb = (lg & 1) << 3;
      long long a[4], b[4];
#pragma unroll
      for (int m = 0; m < 4; ++m) {
        int rr = wm * 64 + m * 16 + lr;
        a[m] = *(const long long*)&Asm[rr * 256 + ((lseg ^ lr) << 4) + hb];
      }
#pragma unroll
      for (int n = 0; n < 4; ++n) {
        int rr = wn * 64 + n * 16 + lr;
        b[n] = *(const long long*)&Bsm[rr * 256 + ((lseg ^ lr) << 4) + hb];
      }
#pragma unroll
      for (int m = 0; m < 4; ++m)
#pragma unroll
        for (int n = 0; n < 4; ++n)
          acc[m][n] = __builtin_amdgcn_mfma_f32_16x16x32_fp8_fp8(a[m], b[n], acc[m][n], 0, 0, 0);
    }
  }

  const float SC = 6.103515625e-05f;  // 2^-14 (h x256, w x64)
  float rs[4][4];
#pragma unroll
  for (int m = 0; m < 4; ++m)
#pragma unroll
    for (int g = 0; g < 4; ++g) rs[m][g] = 0.f;
#pragma unroll
  for (int m = 0; m < 4; ++m) {
#pragma unroll
    for (int n = 0; n < 4; ++n) {
      float bvv = bv[v0 + wn * 64 + n * 16 + lr];
#pragma unroll
      for (int g = 0; g < 4; ++g) rs[m][g] += __expf(acc[m][n][g] * SC + bvv);
    }
  }
#pragma unroll
  for (int m = 0; m < 4; ++m)
#pragma unroll
    for (int g = 0; g < 4; ++g) {
      float v = rs[m][g];
      v += __shfl_xor(v, 1);
      v += __shfl_xor(v, 2);
      v += __shfl_xor(v, 4);
      v += __shfl_xor(v, 8);
      rs[m][g] = v;
    }
  __syncthreads();   // Asm/Bsm dead; red2 overlay becomes valid
  if (lr == 0) {
#pragma unroll
    for (int m = 0; m < 4; ++m)
#pragma unroll
      for (int g = 0; g < 4; ++g)
        red2[wn * 128 + wm * 64 + m * 16 + lg * 4 + g] = rs[m][g];
  }
  __syncthreads();
  if (t < 128) dpart[vt * NR + r0 + t] = red2[t] + red2[128 + t];
}

// ---- reduce partial denominators ----
__global__ void k_reduce(const float* __restrict__ dpart, float* __restrict__ dsum) {
  int r = blockIdx.x * 256 + threadIdx.x;
  float s = 0.f;
  for (int vt = 0; vt < 250; ++vt) s += dpart[vt * NR + r];
  dsum[r] = s;
}

// ---- emission numerators via fp8 MFMA: one 64-thread block per (b,half) ----
__global__ __launch_bounds__(64) void k_emis(const unsigned char* __restrict__ hb8,
                                             const unsigned char* __restrict__ Wv8,
                                             const float* __restrict__ bv,
                                             const float* __restrict__ dsum,
                                             const int* __restrict__ src,
                                             float* __restrict__ em) {
  __shared__ unsigned char A8[48 * 256];
  __shared__ unsigned char B8[48 * 256];
  int t = threadIdx.x;
  int bh = blockIdx.x;
  int b = bh & 31, half = bh >> 5;
  int row4 = t >> 4, seg = t & 15;
  int rbase = half * 1536 + b * 48;
#pragma unroll
  for (int c = 0; c < 12; ++c) {
    int row = c * 4 + row4;
    int gseg = seg ^ (row & 15);
    gload_lds16(&hb8[(rbase + row) * 256 + gseg * 16], &A8[c * 1024]);
    int sv = src[b * 48 + row];
    gload_lds16(&Wv8[sv * 256 + gseg * 16], &B8[c * 1024]);
  }
  __syncthreads();
  int lg = t >> 4, lr = t & 15;
  f32x4 acc[3][3];
#pragma unroll
  for (int m = 0; m < 3; ++m)
#pragma unroll
    for (int n = 0; n < 3; ++n) acc[m][n] = (f32x4){0.f, 0.f, 0.f, 0.f};
#pragma unroll
  for (int kk = 0; kk < 8; ++kk) {
    long long a[3], bb[3];
#pragma unroll
    for (int m = 0; m < 3; ++m) {
      int rr = m * 16 + lr;
      int off = rr * 256 + ((((kk << 1) | (lg >> 1)) ^ (rr & 15)) << 4) + ((lg & 1) << 3);
      a[m] = *(const long long*)&A8[off];
      bb[m] = *(const long long*)&B8[off];
    }
#pragma unroll
    for (int m = 0; m < 3; ++m)
#pragma unroll
      for (int n = 0; n < 3; ++n)
        acc[m][n] = __builtin_amdgcn_mfma_f32_16x16x32_fp8_fp8(a[m], bb[n], acc[m][n], 0, 0, 0);
  }
  const float SC = 6.103515625e-05f;
#pragma unroll
  for (int n = 0; n < 3; ++n) {
    int i = n * 16 + lr;
    int sv = src[b * 48 + i];
    float bvv = bv[sv];
#pragma unroll
    for (int m = 0; m < 3; ++m) {
#pragma unroll
      for (int g = 0; g < 4; ++g) {
        int j = m * 16 + lg * 4 + g;
        float val = __expf(acc[m][n][g] * SC + bvv) / dsum[rbase + j];
        em[b * 4608 + (half * 48 + j) * 48 + i] = val;
      }
    }
  }
}

// ---- fused HMM forward/backward: blocks 0..31 forward(batch), 32..63 backward(batch) ----
__global__ __launch_bounds__(192) void k_fb(const float* __restrict__ Atr, const float* __restrict__ pi,
                                            const float* __restrict__ em, float* __restrict__ alph,
                                            float* __restrict__ betas, float* __restrict__ out1) {
  __shared__ float A_st[96 * 97];
  __shared__ float em_lds[48 * 97];
  __shared__ __align__(16) float vec_lds[96];
  __shared__ float red[3];
  int t = threadIdx.x;
  int bid = blockIdx.x;
  int b = bid & 31;
  int role = bid >> 5;
  int col = t >> 1, half = t & 1;
  int base = b * 4608;

  for (int idx = t; idx < 96 * 96; idx += 192) {
    int s = idx / 96, tt = idx % 96;
    A_st[s * 97 + tt] = Atr[b * 9216 + idx];
  }
  for (int idx = t; idx < 96 * 48; idx += 192) {
    int s = idx / 48, i = idx % 48;
    em_lds[i * 97 + s] = em[base + idx];
  }
  __syncthreads();

  float Areg[48];
  if (role == 0) {
#pragma unroll
    for (int ss = 0; ss < 48; ++ss) Areg[ss] = A_st[(half * 48 + ss) * 97 + col];

    float llsum;
    {
      float v = pi[b * 96 + col] * em_lds[0 * 97 + col];
      float ws = half ? 0.f : v;
      ws = wave_sum(ws);
      if ((t & 63) == 0) red[t >> 6] = ws;
      __syncthreads();
      float c = red[0] + red[1] + red[2];
      float a = v / c;
      if (!half) {
        vec_lds[col] = a;
        alph[base + col] = a;
      }
      llsum = logf(c);
      __syncthreads();
    }
    for (int i = 1; i < 48; ++i) {
      float p = 0.f;
      const float4* ap = (const float4*)&vec_lds[half * 48];
#pragma unroll
      for (int q = 0; q < 12; ++q) {
        float4 av = ap[q];
        p += av.x * Areg[4 * q] + av.y * Areg[4 * q + 1] + av.z * Areg[4 * q + 2] + av.w * Areg[4 * q + 3];
      }
      p += __shfl_xor(p, 1);
      float an = p * em_lds[i * 97 + col];
      float ws = half ? 0.f : an;
      ws = wave_sum(ws);
      if ((t & 63) == 0) red[t >> 6] = ws;
      __syncthreads();
      float c = red[0] + red[1] + red[2];
      float a = an / c;
      if (!half) {
        vec_lds[col] = a;
        alph[base + i * 96 + col] = a;
      }
      llsum += logf(c);
      __syncthreads();
    }
    if (t == 0) out1[b] = -llsum;
  } else {
#pragma unroll
    for (int tt = 0; tt < 48; ++tt) Areg[tt] = A_st[col * 97 + half * 48 + tt];

    if (!half) {
      betas[base + 47 * 96 + col] = 1.0f;
      vec_lds[col] = em_lds[47 * 97 + col];
    }
    __syncthreads();
    for (int i = 46; i >= 0; --i) {
      float p = 0.f;
      const float4* ep = (const float4*)&vec_lds[half * 48];
#pragma unroll
      for (int q = 0; q < 12; ++q) {
        float4 ev = ep[q];
        p += ev.x * Areg[4 * q] + ev.y * Areg[4 * q + 1] + ev.z * Areg[4 * q + 2] + ev.w * Areg[4 * q + 3];
      }
      p += __shfl_xor(p, 1);
      float ws = half ? 0.f : p;
      ws = wave_sum(ws);
      if ((t & 63) == 0) red[t >> 6] = ws;
      __syncthreads();
      float c = red[0] + red[1] + red[2];
      float bt = p / c;
      if (!half) {
        betas[base + i * 96 + col] = bt;
        vec_lds[col] = em_lds[i * 97 + col] * bt;
      }
      __syncthreads();
    }
  }
}

// ---- gamma = alpha*beta, renormalized per (b,i); write transposed [b][s][i] ----
__global__ __launch_bounds__(128) void k_gamma(const float* __restrict__ alph,
                                               const float* __restrict__ betas,
                                               float* __restrict__ out0) {
  __shared__ float red[2];
  int b = blockIdx.x, i = blockIdx.y;
  int t = threadIdx.x;
  float g = 0.f;
  if (t < 96) g = alph[b * 4608 + i * 96 + t] * betas[b * 4608 + i * 96 + t];
  float ws = wave_sum(g);
  if ((t & 63) == 0) red[t >> 6] = ws;
  __syncthreads();
  float c = red[0] + red[1];
  if (t < 96) out0[b * 4608 + t * 48 + i] = g / c;
}

extern "C" void kernel_launch(void* const* d_in, const int* in_sizes, int n_in,
                              void* d_out, int out_size, void* d_ws, size_t ws_size,
                              hipStream_t stream) {
  const float* emb = (const float*)d_in[0];
  const float* Wb  = (const float*)d_in[1];
  const float* Wh  = (const float*)d_in[2];
  const float* bh  = (const float*)d_in[3];
  const float* Wv  = (const float*)d_in[4];
  const float* bv  = (const float*)d_in[5];
  const float* Atr = (const float*)d_in[6];
  const float* pi  = (const float*)d_in[7];
  const int* tc    = (const int*)d_in[8];
  const int* tcn   = (const int*)d_in[9];
  const int* src   = (const int*)d_in[10];

  float* out0 = (float*)d_out;
  float* out1 = out0 + NB * NS * NI;

  char* ws = (char*)d_ws;
  unsigned char* wv8 = (unsigned char*)(ws);                    //  8,192,000 B
  unsigned char* hb8 = (unsigned char*)(ws + 8192000);          //    786,432 B
  float* dpart       = (float*)(ws + 8978432);                  //  3,072,000 B
  float* betas       = (float*)(ws + 8978432);                  //  reuse: dpart dead after k_reduce
  float* dsum        = (float*)(ws + 12050432);                 //     12,288 B
  float* em          = (float*)(ws + 12062720);                 //    589,824 B
  float* alph        = (float*)(ws + 12652544);                 //    589,824 B
  unsigned short* wbt = (unsigned short*)(ws + 13242368);       //    163,840 B
  unsigned short* wht = (unsigned short*)(ws + 13406208);       //     65,536 B
  unsigned short* xb  = (unsigned short*)(ws + 13471744);       //    786,432 B

  k_transpose<<<dim3(500, 4), 256, 0, stream>>>(Wv, wv8);
  k_t2b<<<dim3(10, 2), 256, 0, stream>>>(Wb, wbt, 640, 128);
  k_t2b<<<dim3(2, 4), 256, 0, stream>>>(Wh, wht, 128, 256);
  k_xb<<<48, 256, 0, stream>>>(emb, wbt, tc, tcn, xb);
  k_h<<<dim3(24, 2), 256, 0, stream>>>(xb, wht, bh, hb8);
  k_denom<<<6000, 256, 0, stream>>>(hb8, wv8, bv, dpart);
  k_reduce<<<12, 256, 0, stream>>>(dpart, dsum);
  k_emis<<<64, 64, 0, stream>>>(hb8, wv8, bv, dsum, src, em);
  k_fb<<<64, 192, 0, stream>>>(Atr, pi, em, alph, betas, out1);
  k_gamma<<<dim3(32, 48), 128, 0, stream>>>(alph, betas, out0);
}

// Round 7
// 159.852 us; speedup vs baseline: 1.7616x; 1.0107x over previous
//
#include <hip/hip_runtime.h>
#include <hip/hip_bf16.h>

#define NB 32
#define NJ 48
#define NI 48
#define NCTX 5
#define NE 128
#define NH 256
#define NVS 32000
#define NS 96
#define NR 3072   // 2*B*J rows

typedef __attribute__((ext_vector_type(8))) short bf16x8;
typedef __attribute__((ext_vector_type(4))) float f32x4;

__device__ __forceinline__ unsigned short f2b(float f) {
  __hip_bfloat16 h = __float2bfloat16(f);
  return *reinterpret_cast<unsigned short*>(&h);
}
__device__ __forceinline__ float wave_sum(float v) {
  v += __shfl_xor(v, 1);
  v += __shfl_xor(v, 2);
  v += __shfl_xor(v, 4);
  v += __shfl_xor(v, 8);
  v += __shfl_xor(v, 16);
  v += __shfl_xor(v, 32);
  return v;
}
__device__ __forceinline__ void gload_lds16(const void* g, void* l) {
  __builtin_amdgcn_global_load_lds(
      (const __attribute__((address_space(1))) void*)g,
      (__attribute__((address_space(3))) void*)l, 16, 0, 0);
}

// ---- W_vocab [256][32000] f32 -> Wv8 [32000][256] fp8 e4m3, scaled x64 ----
__global__ __launch_bounds__(256) void k_transpose(const float* __restrict__ Wv,
                                                   unsigned char* __restrict__ Wv8) {
  __shared__ float tile[64][65];
  int t = threadIdx.x;
  int v0 = blockIdx.x * 64, k0 = blockIdx.y * 64;
  {
    int kr = t >> 4, vq = t & 15;
#pragma unroll
    for (int it = 0; it < 4; ++it) {
      float4 v = *(const float4*)&Wv[(k0 + kr + 16 * it) * NVS + v0 + vq * 4];
      tile[kr + 16 * it][vq * 4 + 0] = v.x;
      tile[kr + 16 * it][vq * 4 + 1] = v.y;
      tile[kr + 16 * it][vq * 4 + 2] = v.z;
      tile[kr + 16 * it][vq * 4 + 3] = v.w;
    }
  }
  __syncthreads();
  {
    int vl = t >> 2, kq = t & 3;
    unsigned int q8[4];
#pragma unroll
    for (int d = 0; d < 4; ++d) {
      float f0 = tile[kq * 16 + d * 4 + 0][vl] * 64.0f;
      float f1 = tile[kq * 16 + d * 4 + 1][vl] * 64.0f;
      float f2 = tile[kq * 16 + d * 4 + 2][vl] * 64.0f;
      float f3 = tile[kq * 16 + d * 4 + 3][vl] * 64.0f;
      int w = __builtin_amdgcn_cvt_pk_fp8_f32(f0, f1, 0, false);
      w = __builtin_amdgcn_cvt_pk_fp8_f32(f2, f3, w, true);
      q8[d] = (unsigned int)w;
    }
    *(uint4*)&Wv8[(v0 + vl) * 256 + k0 + kq * 16] = *(uint4*)q8;
  }
}

// ---- generic transpose-convert: src [R][C] f32 -> dst [C][R] bf16 ----
__global__ __launch_bounds__(256) void k_t2b(const float* __restrict__ src,
                                             unsigned short* __restrict__ dst,
                                             int R, int C) {
  __shared__ float tile[64][65];
  int t = threadIdx.x;
  int r0 = blockIdx.x * 64, c0 = blockIdx.y * 64;
  {
    int rr = t >> 4, cq = t & 15;
#pragma unroll
    for (int it = 0; it < 4; ++it) {
      float4 v = *(const float4*)&src[(r0 + rr + 16 * it) * C + c0 + cq * 4];
      tile[rr + 16 * it][cq * 4 + 0] = v.x;
      tile[rr + 16 * it][cq * 4 + 1] = v.y;
      tile[rr + 16 * it][cq * 4 + 2] = v.z;
      tile[rr + 16 * it][cq * 4 + 3] = v.w;
    }
  }
  __syncthreads();
  {
    int cc = t >> 2, rq = t & 3;
    unsigned short pk[16];
#pragma unroll
    for (int q = 0; q < 16; ++q) pk[q] = f2b(tile[rq * 16 + q][cc]);
    *(uint4*)&dst[(c0 + cc) * R + r0 + rq * 16] = *(uint4*)&pk[0];
    *(uint4*)&dst[(c0 + cc) * R + r0 + rq * 16 + 8] = *(uint4*)&pk[8];
  }
}

// ---- GEMM1: xb[3072][128] bf16 = gather(emb) @ Wb ; MFMA, 32-row tiles ----
__global__ __launch_bounds__(256) void k_xb(const float* __restrict__ emb,
                                            const unsigned short* __restrict__ Wbt,
                                            const int* __restrict__ tc, const int* __restrict__ tcn,
                                            unsigned short* __restrict__ xb) {
  __shared__ unsigned short Ax[32 * 72];
  __shared__ unsigned short Bw[128 * 72];
  __shared__ unsigned short xout[32 * 136];
  int t = threadIdx.x;
  int r0 = blockIdx.x * 32;
  int wave = t >> 6, lane = t & 63;
  int wm = wave >> 1, wn = wave & 1;
  int lg = lane >> 4, lr = lane & 15;
  int arow = t >> 3, aseg = t & 7;       // 32 rows x 8 segs(16B of bf16 = 8 elems)
  int r = r0 + arow;
  int half = r / 1536, rem = r % 1536, bb = rem / 48, jj = rem % 48;
  const int* ids = half ? tcn : tc;
  int brow = t >> 1, bseg = t & 1;

  f32x4 acc[4];
#pragma unroll
  for (int n = 0; n < 4; ++n) acc[n] = (f32x4){0.f, 0.f, 0.f, 0.f};

  for (int step = 0; step < 10; ++step) {
    int k0 = step * 64;
    int p = step >> 1;
    int e0 = (step & 1) * 64;
    {
      int id = ids[bb * 240 + jj * 5 + p];
      const float4* er = (const float4*)&emb[id * 128 + e0 + aseg * 8];
      float4 v0 = er[0], v1 = er[1];
      unsigned short pk[8];
      pk[0] = f2b(v0.x); pk[1] = f2b(v0.y); pk[2] = f2b(v0.z); pk[3] = f2b(v0.w);
      pk[4] = f2b(v1.x); pk[5] = f2b(v1.y); pk[6] = f2b(v1.z); pk[7] = f2b(v1.w);
      *(uint4*)&Ax[arow * 72 + aseg * 8] = *(uint4*)&pk[0];
    }
    {
      const uint4* wp = (const uint4*)&Wbt[brow * 640 + k0 + bseg * 32];
      uint4* dp = (uint4*)&Bw[brow * 72 + bseg * 32];
      uint4 w0 = wp[0], w1 = wp[1], w2 = wp[2], w3 = wp[3];
      dp[0] = w0; dp[1] = w1; dp[2] = w2; dp[3] = w3;
    }
    __syncthreads();
#pragma unroll
    for (int kk = 0; kk < 2; ++kk) {
      bf16x8 a = *(const bf16x8*)&Ax[(wm * 16 + lr) * 72 + kk * 32 + lg * 8];
#pragma unroll
      for (int n = 0; n < 4; ++n) {
        bf16x8 b = *(const bf16x8*)&Bw[(wn * 64 + n * 16 + lr) * 72 + kk * 32 + lg * 8];
        acc[n] = __builtin_amdgcn_mfma_f32_16x16x32_bf16(a, b, acc[n], 0, 0, 0);
      }
    }
    __syncthreads();
  }
#pragma unroll
  for (int n = 0; n < 4; ++n)
#pragma unroll
    for (int g = 0; g < 4; ++g)
      xout[(wm * 16 + lg * 4 + g) * 136 + wn * 64 + n * 16 + lr] = f2b(acc[n][g]);
  __syncthreads();
  {
    int orow = t >> 3, os = t & 7;
    *(uint4*)&xb[(r0 + orow) * 128 + os * 16] = *(uint4*)&xout[orow * 136 + os * 16];
    *(uint4*)&xb[(r0 + orow) * 128 + os * 16 + 8] = *(uint4*)&xout[orow * 136 + os * 16 + 8];
  }
}

// ---- GEMM2: h = tanh(xb @ Wh + bh) -> fp8 hb8 [3072][256] ; 128x128x128 ----
__global__ __launch_bounds__(256) void k_h(const unsigned short* __restrict__ xb,
                                           const unsigned short* __restrict__ Wht,
                                           const float* __restrict__ bh,
                                           unsigned char* __restrict__ hb8) {
  __shared__ char smem[69632];
  unsigned short* Asm = (unsigned short*)smem;            // [128][136]
  unsigned short* Bsm = (unsigned short*)(smem + 34816);  // [128][136]
  unsigned char* o8 = (unsigned char*)smem;               // reuse: [128][144]
  int t = threadIdx.x;
  int r0 = blockIdx.x * 128, n0 = blockIdx.y * 128;
  int wave = t >> 6, lane = t & 63;
  int wm = wave >> 1, wn = wave & 1;
  int lg = lane >> 4, lr = lane & 15;
  {
    int row = t >> 1, seg = t & 1;
#pragma unroll
    for (int i = 0; i < 8; ++i) {
      *(uint4*)&Asm[row * 136 + seg * 64 + i * 8] = *(const uint4*)&xb[(r0 + row) * 128 + seg * 64 + i * 8];
      *(uint4*)&Bsm[row * 136 + seg * 64 + i * 8] = *(const uint4*)&Wht[(n0 + row) * 128 + seg * 64 + i * 8];
    }
  }
  __syncthreads();
  f32x4 acc[4][4];
#pragma unroll
  for (int m = 0; m < 4; ++m)
#pragma unroll
    for (int n = 0; n < 4; ++n) acc[m][n] = (f32x4){0.f, 0.f, 0.f, 0.f};
#pragma unroll
  for (int kk = 0; kk < 4; ++kk) {
    bf16x8 a[4], b[4];
#pragma unroll
    for (int m = 0; m < 4; ++m)
      a[m] = *(const bf16x8*)&Asm[(wm * 64 + m * 16 + lr) * 136 + kk * 32 + lg * 8];
#pragma unroll
    for (int n = 0; n < 4; ++n)
      b[n] = *(const bf16x8*)&Bsm[(wn * 64 + n * 16 + lr) * 136 + kk * 32 + lg * 8];
#pragma unroll
    for (int m = 0; m < 4; ++m)
#pragma unroll
      for (int n = 0; n < 4; ++n)
        acc[m][n] = __builtin_amdgcn_mfma_f32_16x16x32_bf16(a[m], b[n], acc[m][n], 0, 0, 0);
  }
  __syncthreads();
#pragma unroll
  for (int n = 0; n < 4; ++n) {
    int cl = wn * 64 + n * 16 + lr;
    float bvv = bh[n0 + cl];
#pragma unroll
    for (int m = 0; m < 4; ++m) {
#pragma unroll
      for (int g = 0; g < 4; ++g) {
        int rl = wm * 64 + m * 16 + lg * 4 + g;
        float hv = tanhf(acc[m][n][g] + bvv);
        int p8 = __builtin_amdgcn_cvt_pk_fp8_f32(hv * 256.0f, 0.0f, 0, false);
        o8[rl * 144 + cl] = (unsigned char)(p8 & 0xFF);
      }
    }
  }
  __syncthreads();
  {
    int row = t >> 1, seg = t & 1;
#pragma unroll
    for (int i = 0; i < 4; ++i)
      *(uint4*)&hb8[(r0 + row) * 256 + n0 + seg * 64 + i * 16] = *(uint4*)&o8[row * 144 + seg * 64 + i * 16];
  }
}

// ---- denominator GEMM: rowsum of exp((h8 @ Wv8)*2^-14 + bv), fp8 MFMA ----
// A-resident (32KB, staged once), 2 vocab tiles per block, B double-buffered
// 8KB K-chunks with stage-ahead + one barrier per step. Swizzles: A seg^(row&15)
// (256B rows), B seg^((row>>1)&3) (64B chunks) on both source and read.
__global__ __launch_bounds__(256) void k_denom(const unsigned char* __restrict__ hb8,
                                               const unsigned char* __restrict__ Wv8,
                                               const float* __restrict__ bv,
                                               float* __restrict__ dpart) {
  __shared__ __align__(16) unsigned char Asm[32768];     // [128][256]
  __shared__ __align__(16) unsigned char Bsm[2][8192];   // [128][64] x2
  __shared__ float red2[2][128];
  int t = threadIdx.x;
  int bid = blockIdx.x;                 // 3000 = 8 * 375
  int xcd = bid & 7;
  int pos = bid >> 3;
  int tile = xcd * 375 + pos;
  int vtp = tile / 24, rt = tile % 24;  // vocab-pair, row tile
  int r0 = rt * 128;
  int wave = t >> 6, lane = t & 63;
  int wm = wave >> 1, wn = wave & 1;
  int lg = lane >> 4, lr = lane & 15;

  // ---- stage A once: 32 chunks of 4 rows x 256B ----
  {
    int rloc = lane >> 4, seg = lane & 15;
#pragma unroll
    for (int c = 0; c < 8; ++c) {
      int chunk = wave * 8 + c;
      int row = chunk * 4 + rloc;
      int gseg = seg ^ (row & 15);
      gload_lds16(&hb8[(r0 + row) * 256 + gseg * 16], &Asm[chunk * 1024]);
    }
  }
  // ---- stage B(step 0) into buf 0 ----
  int brloc = lane >> 2, bseg = lane & 3;
#pragma unroll
  for (int c = 0; c < 2; ++c) {
    int i = wave * 2 + c;
    int row = i * 16 + brloc;
    int gseg = bseg ^ ((row >> 1) & 3);
    gload_lds16(&Wv8[(vtp * 256 + row) * 256 + 0 * 64 + gseg * 16], &Bsm[0][i * 1024]);
  }
  __syncthreads();

  const float SC = 6.103515625e-05f;  // 2^-14 (h x256, w x64)
  f32x4 acc[4][4];
#pragma unroll
  for (int m = 0; m < 4; ++m)
#pragma unroll
    for (int n = 0; n < 4; ++n) acc[m][n] = (f32x4){0.f, 0.f, 0.f, 0.f};

#pragma unroll
  for (int step = 0; step < 8; ++step) {
    int vt = step >> 2, ks = step & 3, buf = step & 1;
    // stage-ahead: issue next B chunk into the other buffer
    if (step < 7) {
      int ns = step + 1;
      int nvt = ns >> 2, nks = ns & 3, nbuf = ns & 1;
#pragma unroll
      for (int c = 0; c < 2; ++c) {
        int i = wave * 2 + c;
        int row = i * 16 + brloc;
        int gseg = bseg ^ ((row >> 1) & 3);
        gload_lds16(&Wv8[((vtp * 2 + nvt) * 128 + row) * 256 + nks * 64 + gseg * 16],
                    &Bsm[nbuf][i * 1024]);
      }
    }
    // compute on buf (ready since previous barrier)
#pragma unroll
    for (int kk = 0; kk < 2; ++kk) {
      int lsa = ks * 4 + kk * 2 + (lg >> 1);
      int sb = kk * 2 + (lg >> 1);
      int hb = (lg & 1) << 3;
      long long a[4], b[4];
#pragma unroll
      for (int m = 0; m < 4; ++m) {
        int rr = wm * 64 + m * 16 + lr;
        a[m] = *(const long long*)&Asm[rr * 256 + ((lsa ^ lr) << 4) + hb];
      }
#pragma unroll
      for (int n = 0; n < 4; ++n) {
        int rr = wn * 64 + n * 16 + lr;
        b[n] = *(const long long*)&Bsm[buf][rr * 64 + ((sb ^ ((rr >> 1) & 3)) << 4) + hb];
      }
#pragma unroll
      for (int m = 0; m < 4; ++m)
#pragma unroll
        for (int n = 0; n < 4; ++n)
          acc[m][n] = __builtin_amdgcn_mfma_f32_16x16x32_fp8_fp8(a[m], b[n], acc[m][n], 0, 0, 0);
    }
    // per-vocab-tile epilogue after its last K-step
    if (ks == 3) {
      int v0 = (vtp * 2 + vt) * 128;
      float rs[4][4];
#pragma unroll
      for (int m = 0; m < 4; ++m)
#pragma unroll
        for (int g = 0; g < 4; ++g) rs[m][g] = 0.f;
#pragma unroll
      for (int m = 0; m < 4; ++m) {
#pragma unroll
        for (int n = 0; n < 4; ++n) {
          float bvv = bv[v0 + wn * 64 + n * 16 + lr];
#pragma unroll
          for (int g = 0; g < 4; ++g) rs[m][g] += __expf(acc[m][n][g] * SC + bvv);
          acc[m][n] = (f32x4){0.f, 0.f, 0.f, 0.f};   // reset for next vt
        }
      }
#pragma unroll
      for (int m = 0; m < 4; ++m)
#pragma unroll
        for (int g = 0; g < 4; ++g) {
          float v = rs[m][g];
          v += __shfl_xor(v, 1);
          v += __shfl_xor(v, 2);
          v += __shfl_xor(v, 4);
          v += __shfl_xor(v, 8);
          rs[m][g] = v;
        }
      if (lr == 0) {
#pragma unroll
        for (int m = 0; m < 4; ++m)
#pragma unroll
          for (int g = 0; g < 4; ++g)
            red2[wn][wm * 64 + m * 16 + lg * 4 + g] = rs[m][g];
      }
      __syncthreads();   // red2 ready (doubles as step-end barrier)
      if (t < 128) dpart[(vtp * 2 + vt) * NR + r0 + t] = red2[0][t] + red2[1][t];
    } else {
      __syncthreads();   // step-end: drains next-stage loads, guards buffer WAR
    }
  }
}

// ---- reduce partial denominators ----
__global__ void k_reduce(const float* __restrict__ dpart, float* __restrict__ dsum) {
  int r = blockIdx.x * 256 + threadIdx.x;
  float s = 0.f;
  for (int vt = 0; vt < 250; ++vt) s += dpart[vt * NR + r];
  dsum[r] = s;
}

// ---- emission numerators via fp8 MFMA: one 64-thread block per (b,half) ----
__global__ __launch_bounds__(64) void k_emis(const unsigned char* __restrict__ hb8,
                                             const unsigned char* __restrict__ Wv8,
                                             const float* __restrict__ bv,
                                             const float* __restrict__ dsum,
                                             const int* __restrict__ src,
                                             float* __restrict__ em) {
  __shared__ unsigned char A8[48 * 256];
  __shared__ unsigned char B8[48 * 256];
  int t = threadIdx.x;
  int bh = blockIdx.x;
  int b = bh & 31, half = bh >> 5;
  int row4 = t >> 4, seg = t & 15;
  int rbase = half * 1536 + b * 48;
#pragma unroll
  for (int c = 0; c < 12; ++c) {
    int row = c * 4 + row4;
    int gseg = seg ^ (row & 15);
    gload_lds16(&hb8[(rbase + row) * 256 + gseg * 16], &A8[c * 1024]);
    int sv = src[b * 48 + row];
    gload_lds16(&Wv8[sv * 256 + gseg * 16], &B8[c * 1024]);
  }
  __syncthreads();
  int lg = t >> 4, lr = t & 15;
  f32x4 acc[3][3];
#pragma unroll
  for (int m = 0; m < 3; ++m)
#pragma unroll
    for (int n = 0; n < 3; ++n) acc[m][n] = (f32x4){0.f, 0.f, 0.f, 0.f};
#pragma unroll
  for (int kk = 0; kk < 8; ++kk) {
    long long a[3], bb[3];
#pragma unroll
    for (int m = 0; m < 3; ++m) {
      int rr = m * 16 + lr;
      int off = rr * 256 + ((((kk << 1) | (lg >> 1)) ^ (rr & 15)) << 4) + ((lg & 1) << 3);
      a[m] = *(const long long*)&A8[off];
      bb[m] = *(const long long*)&B8[off];
    }
#pragma unroll
    for (int m = 0; m < 3; ++m)
#pragma unroll
      for (int n = 0; n < 3; ++n)
        acc[m][n] = __builtin_amdgcn_mfma_f32_16x16x32_fp8_fp8(a[m], bb[n], acc[m][n], 0, 0, 0);
  }
  const float SC = 6.103515625e-05f;
#pragma unroll
  for (int n = 0; n < 3; ++n) {
    int i = n * 16 + lr;
    int sv = src[b * 48 + i];
    float bvv = bv[sv];
#pragma unroll
    for (int m = 0; m < 3; ++m) {
#pragma unroll
      for (int g = 0; g < 4; ++g) {
        int j = m * 16 + lg * 4 + g;
        float val = __expf(acc[m][n][g] * SC + bvv) / dsum[rbase + j];
        em[b * 4608 + (half * 48 + j) * 48 + i] = val;
      }
    }
  }
}

// ---- fused HMM forward/backward: blocks 0..31 forward(batch), 32..63 backward(batch) ----
__global__ __launch_bounds__(192) void k_fb(const float* __restrict__ Atr, const float* __restrict__ pi,
                                            const float* __restrict__ em, float* __restrict__ alph,
                                            float* __restrict__ betas, float* __restrict__ out1) {
  __shared__ float A_st[96 * 97];
  __shared__ float em_lds[48 * 97];
  __shared__ __align__(16) float vec_lds[96];
  __shared__ float red[3];
  int t = threadIdx.x;
  int bid = blockIdx.x;
  int b = bid & 31;
  int role = bid >> 5;
  int col = t >> 1, half = t & 1;
  int base = b * 4608;

  for (int idx = t; idx < 96 * 96; idx += 192) {
    int s = idx / 96, tt = idx % 96;
    A_st[s * 97 + tt] = Atr[b * 9216 + idx];
  }
  for (int idx = t; idx < 96 * 48; idx += 192) {
    int s = idx / 48, i = idx % 48;
    em_lds[i * 97 + s] = em[base + idx];
  }
  __syncthreads();

  float Areg[48];
  if (role == 0) {
#pragma unroll
    for (int ss = 0; ss < 48; ++ss) Areg[ss] = A_st[(half * 48 + ss) * 97 + col];

    float llsum;
    {
      float v = pi[b * 96 + col] * em_lds[0 * 97 + col];
      float ws = half ? 0.f : v;
      ws = wave_sum(ws);
      if ((t & 63) == 0) red[t >> 6] = ws;
      __syncthreads();
      float c = red[0] + red[1] + red[2];
      float a = v / c;
      if (!half) {
        vec_lds[col] = a;
        alph[base + col] = a;
      }
      llsum = logf(c);
      __syncthreads();
    }
    for (int i = 1; i < 48; ++i) {
      float p = 0.f;
      const float4* ap = (const float4*)&vec_lds[half * 48];
#pragma unroll
      for (int q = 0; q < 12; ++q) {
        float4 av = ap[q];
        p += av.x * Areg[4 * q] + av.y * Areg[4 * q + 1] + av.z * Areg[4 * q + 2] + av.w * Areg[4 * q + 3];
      }
      p += __shfl_xor(p, 1);
      float an = p * em_lds[i * 97 + col];
      float ws = half ? 0.f : an;
      ws = wave_sum(ws);
      if ((t & 63) == 0) red[t >> 6] = ws;
      __syncthreads();
      float c = red[0] + red[1] + red[2];
      float a = an / c;
      if (!half) {
        vec_lds[col] = a;
        alph[base + i * 96 + col] = a;
      }
      llsum += logf(c);
      __syncthreads();
    }
    if (t == 0) out1[b] = -llsum;
  } else {
#pragma unroll
    for (int tt = 0; tt < 48; ++tt) Areg[tt] = A_st[col * 97 + half * 48 + tt];

    if (!half) {
      betas[base + 47 * 96 + col] = 1.0f;
      vec_lds[col] = em_lds[47 * 97 + col];
    }
    __syncthreads();
    for (int i = 46; i >= 0; --i) {
      float p = 0.f;
      const float4* ep = (const float4*)&vec_lds[half * 48];
#pragma unroll
      for (int q = 0; q < 12; ++q) {
        float4 ev = ep[q];
        p += ev.x * Areg[4 * q] + ev.y * Areg[4 * q + 1] + ev.z * Areg[4 * q + 2] + ev.w * Areg[4 * q + 3];
      }
      p += __shfl_xor(p, 1);
      float ws = half ? 0.f : p;
      ws = wave_sum(ws);
      if ((t & 63) == 0) red[t >> 6] = ws;
      __syncthreads();
      float c = red[0] + red[1] + red[2];
      float bt = p / c;
      if (!half) {
        betas[base + i * 96 + col] = bt;
        vec_lds[col] = em_lds[i * 97 + col] * bt;
      }
      __syncthreads();
    }
  }
}

// ---- gamma = alpha*beta, renormalized per (b,i); write transposed [b][s][i] ----
__global__ __launch_bounds__(128) void k_gamma(const float* __restrict__ alph,
                                               const float* __restrict__ betas,
                                               float* __restrict__ out0) {
  __shared__ float red[2];
  int b = blockIdx.x, i = blockIdx.y;
  int t = threadIdx.x;
  float g = 0.f;
  if (t < 96) g = alph[b * 4608 + i * 96 + t] * betas[b * 4608 + i * 96 + t];
  float ws = wave_sum(g);
  if ((t & 63) == 0) red[t >> 6] = ws;
  __syncthreads();
  float c = red[0] + red[1];
  if (t < 96) out0[b * 4608 + t * 48 + i] = g / c;
}

extern "C" void kernel_launch(void* const* d_in, const int* in_sizes, int n_in,
                              void* d_out, int out_size, void* d_ws, size_t ws_size,
                              hipStream_t stream) {
  const float* emb = (const float*)d_in[0];
  const float* Wb  = (const float*)d_in[1];
  const float* Wh  = (const float*)d_in[2];
  const float* bh  = (const float*)d_in[3];
  const float* Wv  = (const float*)d_in[4];
  const float* bv  = (const float*)d_in[5];
  const float* Atr = (const float*)d_in[6];
  const float* pi  = (const float*)d_in[7];
  const int* tc    = (const int*)d_in[8];
  const int* tcn   = (const int*)d_in[9];
  const int* src   = (const int*)d_in[10];

  float* out0 = (float*)d_out;
  float* out1 = out0 + NB * NS * NI;

  char* ws = (char*)d_ws;
  unsigned char* wv8 = (unsigned char*)(ws);                    //  8,192,000 B
  unsigned char* hb8 = (unsigned char*)(ws + 8192000);          //    786,432 B
  float* dpart       = (float*)(ws + 8978432);                  //  3,072,000 B
  float* betas       = (float*)(ws + 8978432);                  //  reuse: dpart dead after k_reduce
  float* dsum        = (float*)(ws + 12050432);                 //     12,288 B
  float* em          = (float*)(ws + 12062720);                 //    589,824 B
  float* alph        = (float*)(ws + 12652544);                 //    589,824 B
  unsigned short* wbt = (unsigned short*)(ws + 13242368);       //    163,840 B
  unsigned short* wht = (unsigned short*)(ws + 13406208);       //     65,536 B
  unsigned short* xb  = (unsigned short*)(ws + 13471744);       //    786,432 B

  k_transpose<<<dim3(500, 4), 256, 0, stream>>>(Wv, wv8);
  k_t2b<<<dim3(10, 2), 256, 0, stream>>>(Wb, wbt, 640, 128);
  k_t2b<<<dim3(2, 4), 256, 0, stream>>>(Wh, wht, 128, 256);
  k_xb<<<96, 256, 0, stream>>>(emb, wbt, tc, tcn, xb);
  k_h<<<dim3(24, 2), 256, 0, stream>>>(xb, wht, bh, hb8);
  k_denom<<<3000, 256, 0, stream>>>(hb8, wv8, bv, dpart);
  k_reduce<<<12, 256, 0, stream>>>(dpart, dsum);
  k_emis<<<64, 64, 0, stream>>>(hb8, wv8, bv, dsum, src, em);
  k_fb<<<64, 192, 0, stream>>>(Atr, pi, em, alph, betas, out1);
  k_gamma<<<dim3(32, 48), 128, 0, stream>>>(alph, betas, out0);
}

// Round 8
// 150.265 us; speedup vs baseline: 1.8740x; 1.0638x over previous
//
#include <hip/hip_runtime.h>
#include <hip/hip_bf16.h>

#define NB 32
#define NJ 48
#define NI 48
#define NCTX 5
#define NE 128
#define NH 256
#define NVS 32000
#define NS 96
#define NR 3072   // 2*B*J rows

typedef __attribute__((ext_vector_type(8))) short bf16x8;
typedef __attribute__((ext_vector_type(4))) float f32x4;

__device__ __forceinline__ unsigned short f2b(float f) {
  __hip_bfloat16 h = __float2bfloat16(f);
  return *reinterpret_cast<unsigned short*>(&h);
}
__device__ __forceinline__ float wave_sum(float v) {
  v += __shfl_xor(v, 1);
  v += __shfl_xor(v, 2);
  v += __shfl_xor(v, 4);
  v += __shfl_xor(v, 8);
  v += __shfl_xor(v, 16);
  v += __shfl_xor(v, 32);
  return v;
}
__device__ __forceinline__ void gload_lds16(const void* g, void* l) {
  __builtin_amdgcn_global_load_lds(
      (const __attribute__((address_space(1))) void*)g,
      (__attribute__((address_space(3))) void*)l, 16, 0, 0);
}

// Global fp8 layouts are 8B-slot permuted for conflict-free ds_read_b64:
//   hb8 (A-style, 256B rows):  slot s (0..31) stored at s ^ (row & 15)
//   Wv8 (B-style, per 64B chunk): slot s (0..7) stored at s ^ ((row>>1) & 7)
// Writers apply unit-permute + half-swap; staging is verbatim; readers XOR.

// ---- W_vocab [256][32000] f32 -> Wv8 [32000][256] fp8 e4m3, scaled x64 ----
__global__ __launch_bounds__(256) void k_transpose(const float* __restrict__ Wv,
                                                   unsigned char* __restrict__ Wv8) {
  __shared__ float tile[64][65];
  int t = threadIdx.x;
  int v0 = blockIdx.x * 64, k0 = blockIdx.y * 64;
  {
    int kr = t >> 4, vq = t & 15;
#pragma unroll
    for (int it = 0; it < 4; ++it) {
      float4 v = *(const float4*)&Wv[(k0 + kr + 16 * it) * NVS + v0 + vq * 4];
      tile[kr + 16 * it][vq * 4 + 0] = v.x;
      tile[kr + 16 * it][vq * 4 + 1] = v.y;
      tile[kr + 16 * it][vq * 4 + 2] = v.z;
      tile[kr + 16 * it][vq * 4 + 3] = v.w;
    }
  }
  __syncthreads();
  {
    int vl = t >> 2, kq = t & 3;
    unsigned int q8[4];
#pragma unroll
    for (int d = 0; d < 4; ++d) {
      float f0 = tile[kq * 16 + d * 4 + 0][vl] * 64.0f;
      float f1 = tile[kq * 16 + d * 4 + 1][vl] * 64.0f;
      float f2 = tile[kq * 16 + d * 4 + 2][vl] * 64.0f;
      float f3 = tile[kq * 16 + d * 4 + 3][vl] * 64.0f;
      int w = __builtin_amdgcn_cvt_pk_fp8_f32(f0, f1, 0, false);
      w = __builtin_amdgcn_cvt_pk_fp8_f32(f2, f3, w, true);
      q8[d] = (unsigned int)w;
    }
    // B-layout permute: unit kq -> kq ^ ((r>>2)&3), halves swapped if (r>>1)&1
    int kqp = kq ^ ((vl >> 2) & 3);
    unsigned int q8s[4];
    if ((vl >> 1) & 1) {
      q8s[0] = q8[2]; q8s[1] = q8[3]; q8s[2] = q8[0]; q8s[3] = q8[1];
    } else {
      q8s[0] = q8[0]; q8s[1] = q8[1]; q8s[2] = q8[2]; q8s[3] = q8[3];
    }
    *(uint4*)&Wv8[(v0 + vl) * 256 + k0 + kqp * 16] = *(uint4*)q8s;
  }
}

// ---- generic transpose-convert: src [R][C] f32 -> dst [C][R] bf16 ----
__global__ __launch_bounds__(256) void k_t2b(const float* __restrict__ src,
                                             unsigned short* __restrict__ dst,
                                             int R, int C) {
  __shared__ float tile[64][65];
  int t = threadIdx.x;
  int r0 = blockIdx.x * 64, c0 = blockIdx.y * 64;
  {
    int rr = t >> 4, cq = t & 15;
#pragma unroll
    for (int it = 0; it < 4; ++it) {
      float4 v = *(const float4*)&src[(r0 + rr + 16 * it) * C + c0 + cq * 4];
      tile[rr + 16 * it][cq * 4 + 0] = v.x;
      tile[rr + 16 * it][cq * 4 + 1] = v.y;
      tile[rr + 16 * it][cq * 4 + 2] = v.z;
      tile[rr + 16 * it][cq * 4 + 3] = v.w;
    }
  }
  __syncthreads();
  {
    int cc = t >> 2, rq = t & 3;
    unsigned short pk[16];
#pragma unroll
    for (int q = 0; q < 16; ++q) pk[q] = f2b(tile[rq * 16 + q][cc]);
    *(uint4*)&dst[(c0 + cc) * R + r0 + rq * 16] = *(uint4*)&pk[0];
    *(uint4*)&dst[(c0 + cc) * R + r0 + rq * 16 + 8] = *(uint4*)&pk[8];
  }
}

// ---- GEMM1: xb[3072][128] bf16 = gather(emb) @ Wb ; MFMA, 32-row tiles ----
__global__ __launch_bounds__(256) void k_xb(const float* __restrict__ emb,
                                            const unsigned short* __restrict__ Wbt,
                                            const int* __restrict__ tc, const int* __restrict__ tcn,
                                            unsigned short* __restrict__ xb) {
  __shared__ unsigned short Ax[32 * 72];
  __shared__ unsigned short Bw[128 * 72];
  __shared__ unsigned short xout[32 * 136];
  int t = threadIdx.x;
  int r0 = blockIdx.x * 32;
  int wave = t >> 6, lane = t & 63;
  int wm = wave >> 1, wn = wave & 1;
  int lg = lane >> 4, lr = lane & 15;
  int arow = t >> 3, aseg = t & 7;
  int r = r0 + arow;
  int half = r / 1536, rem = r % 1536, bb = rem / 48, jj = rem % 48;
  const int* ids = half ? tcn : tc;
  int brow = t >> 1, bseg = t & 1;

  f32x4 acc[4];
#pragma unroll
  for (int n = 0; n < 4; ++n) acc[n] = (f32x4){0.f, 0.f, 0.f, 0.f};

  for (int step = 0; step < 10; ++step) {
    int k0 = step * 64;
    int p = step >> 1;
    int e0 = (step & 1) * 64;
    {
      int id = ids[bb * 240 + jj * 5 + p];
      const float4* er = (const float4*)&emb[id * 128 + e0 + aseg * 8];
      float4 v0 = er[0], v1 = er[1];
      unsigned short pk[8];
      pk[0] = f2b(v0.x); pk[1] = f2b(v0.y); pk[2] = f2b(v0.z); pk[3] = f2b(v0.w);
      pk[4] = f2b(v1.x); pk[5] = f2b(v1.y); pk[6] = f2b(v1.z); pk[7] = f2b(v1.w);
      *(uint4*)&Ax[arow * 72 + aseg * 8] = *(uint4*)&pk[0];
    }
    {
      const uint4* wp = (const uint4*)&Wbt[brow * 640 + k0 + bseg * 32];
      uint4* dp = (uint4*)&Bw[brow * 72 + bseg * 32];
      uint4 w0 = wp[0], w1 = wp[1], w2 = wp[2], w3 = wp[3];
      dp[0] = w0; dp[1] = w1; dp[2] = w2; dp[3] = w3;
    }
    __syncthreads();
#pragma unroll
    for (int kk = 0; kk < 2; ++kk) {
      bf16x8 a = *(const bf16x8*)&Ax[(wm * 16 + lr) * 72 + kk * 32 + lg * 8];
#pragma unroll
      for (int n = 0; n < 4; ++n) {
        bf16x8 b = *(const bf16x8*)&Bw[(wn * 64 + n * 16 + lr) * 72 + kk * 32 + lg * 8];
        acc[n] = __builtin_amdgcn_mfma_f32_16x16x32_bf16(a, b, acc[n], 0, 0, 0);
      }
    }
    __syncthreads();
  }
#pragma unroll
  for (int n = 0; n < 4; ++n)
#pragma unroll
    for (int g = 0; g < 4; ++g)
      xout[(wm * 16 + lg * 4 + g) * 136 + wn * 64 + n * 16 + lr] = f2b(acc[n][g]);
  __syncthreads();
  {
    int orow = t >> 3, os = t & 7;
    *(uint4*)&xb[(r0 + orow) * 128 + os * 16] = *(uint4*)&xout[orow * 136 + os * 16];
    *(uint4*)&xb[(r0 + orow) * 128 + os * 16 + 8] = *(uint4*)&xout[orow * 136 + os * 16 + 8];
  }
}

// ---- GEMM2: h = tanh(xb @ Wh + bh) -> fp8 hb8 [3072][256] (A-layout permuted) ----
__global__ __launch_bounds__(256) void k_h(const unsigned short* __restrict__ xb,
                                           const unsigned short* __restrict__ Wht,
                                           const float* __restrict__ bh,
                                           unsigned char* __restrict__ hb8) {
  __shared__ char smem[69632];
  unsigned short* Asm = (unsigned short*)smem;            // [128][136]
  unsigned short* Bsm = (unsigned short*)(smem + 34816);  // [128][136]
  unsigned char* o8 = (unsigned char*)smem;               // reuse: [128][144]
  int t = threadIdx.x;
  int r0 = blockIdx.x * 128, n0 = blockIdx.y * 128;
  int wave = t >> 6, lane = t & 63;
  int wm = wave >> 1, wn = wave & 1;
  int lg = lane >> 4, lr = lane & 15;
  {
    int row = t >> 1, seg = t & 1;
#pragma unroll
    for (int i = 0; i < 8; ++i) {
      *(uint4*)&Asm[row * 136 + seg * 64 + i * 8] = *(const uint4*)&xb[(r0 + row) * 128 + seg * 64 + i * 8];
      *(uint4*)&Bsm[row * 136 + seg * 64 + i * 8] = *(const uint4*)&Wht[(n0 + row) * 128 + seg * 64 + i * 8];
    }
  }
  __syncthreads();
  f32x4 acc[4][4];
#pragma unroll
  for (int m = 0; m < 4; ++m)
#pragma unroll
    for (int n = 0; n < 4; ++n) acc[m][n] = (f32x4){0.f, 0.f, 0.f, 0.f};
#pragma unroll
  for (int kk = 0; kk < 4; ++kk) {
    bf16x8 a[4], b[4];
#pragma unroll
    for (int m = 0; m < 4; ++m)
      a[m] = *(const bf16x8*)&Asm[(wm * 64 + m * 16 + lr) * 136 + kk * 32 + lg * 8];
#pragma unroll
    for (int n = 0; n < 4; ++n)
      b[n] = *(const bf16x8*)&Bsm[(wn * 64 + n * 16 + lr) * 136 + kk * 32 + lg * 8];
#pragma unroll
    for (int m = 0; m < 4; ++m)
#pragma unroll
      for (int n = 0; n < 4; ++n)
        acc[m][n] = __builtin_amdgcn_mfma_f32_16x16x32_bf16(a[m], b[n], acc[m][n], 0, 0, 0);
  }
  __syncthreads();
#pragma unroll
  for (int n = 0; n < 4; ++n) {
    int cl = wn * 64 + n * 16 + lr;
    float bvv = bh[n0 + cl];
#pragma unroll
    for (int m = 0; m < 4; ++m) {
#pragma unroll
      for (int g = 0; g < 4; ++g) {
        int rl = wm * 64 + m * 16 + lg * 4 + g;
        float hv = tanhf(acc[m][n][g] + bvv);
        int p8 = __builtin_amdgcn_cvt_pk_fp8_f32(hv * 256.0f, 0.0f, 0, false);
        o8[rl * 144 + cl] = (unsigned char)(p8 & 0xFF);
      }
    }
  }
  __syncthreads();
  // permuted store: dest unit p <- logical unit p ^ ((row>>1)&7), halves swapped if row&1
  {
    int row = t >> 1, seg = t & 1;
    int sig = (row >> 1) & 7;
    int swp = row & 1;
#pragma unroll
    for (int i = 0; i < 4; ++i) {
      int p_loc = seg * 4 + i;
      int w_loc = p_loc ^ sig;
      unsigned long long q[2];
      q[0] = *(const unsigned long long*)&o8[row * 144 + w_loc * 16 + swp * 8];
      q[1] = *(const unsigned long long*)&o8[row * 144 + w_loc * 16 + (swp ^ 1) * 8];
      *(uint4*)&hb8[(r0 + row) * 256 + n0 + p_loc * 16] = *(uint4*)q;
    }
  }
}

// ---- denominator GEMM: rowsum of exp((h8 @ Wv8)*2^-14 + bv), fp8 MFMA ----
// A-fragments in registers (filled once from 32KB LDS stage, then LDS reused),
// B double-buffered 8KB chunks, verbatim staging (layouts pre-permuted),
// conflict-free b64 reads, 1 barrier/step, 48KB LDS -> 3 blocks/CU.
__global__ __launch_bounds__(256) void k_denom(const unsigned char* __restrict__ hb8,
                                               const unsigned char* __restrict__ Wv8,
                                               const float* __restrict__ bv,
                                               float* __restrict__ dpart) {
  __shared__ __align__(16) unsigned char smem[49152];
  unsigned char* Asm = smem;                       // [128][256], dead after reg-fill
  float* red2 = (float*)smem;                      // overlay: [2][128]
  unsigned char* bufp[2] = {smem + 32768, smem + 40960};  // B [128][64] x2
  int t = threadIdx.x;
  int bid = blockIdx.x;                 // 3000 = 8 * 375
  int xcd = bid & 7;
  int pos = bid >> 3;
  int tile = xcd * 375 + pos;
  int vtp = tile / 24, rt = tile % 24;
  int r0 = rt * 128;
  int wave = t >> 6, lane = t & 63;
  int wm = wave >> 1, wn = wave & 1;
  int lg = lane >> 4, lr = lane & 15;

  // stage A verbatim: 32 insts x 1KB (rows 4c..4c+3)
#pragma unroll
  for (int c = 0; c < 8; ++c) {
    int inst = wave * 8 + c;
    gload_lds16(&hb8[(r0 + inst * 4 + (lane >> 4)) * 256 + (lane & 15) * 16], &Asm[inst * 1024]);
  }
  // stage B step-0 verbatim: 8 insts x 1KB (rows i*16 + lane>>2, unit lane&3)
#pragma unroll
  for (int c = 0; c < 2; ++c) {
    int i = wave * 2 + c;
    gload_lds16(&Wv8[(vtp * 256 + i * 16 + (lane >> 2)) * 256 + 0 * 64 + (lane & 3) * 16],
                bufp[0] + i * 1024);
  }
  __syncthreads();

  // A-reg fill: 32 b64/lane, swizzled (s ^ lr), then Asm is dead
  long long a_reg[4][8];
#pragma unroll
  for (int m = 0; m < 4; ++m) {
    int rowb = (wm * 64 + m * 16 + lr) * 256;
#pragma unroll
    for (int ks = 0; ks < 4; ++ks)
#pragma unroll
      for (int kk = 0; kk < 2; ++kk)
        a_reg[m][ks * 2 + kk] =
            *(const long long*)&Asm[rowb + (((ks * 8 + kk * 4 + lg) ^ lr) << 3)];
  }

  const float SC = 6.103515625e-05f;  // 2^-14 (h x256, w x64)
  f32x4 acc[4][4];
#pragma unroll
  for (int m = 0; m < 4; ++m)
#pragma unroll
    for (int n = 0; n < 4; ++n) acc[m][n] = (f32x4){0.f, 0.f, 0.f, 0.f};

#pragma unroll
  for (int step = 0; step < 8; ++step) {
    int vt = step >> 2, ks = step & 3, buf = step & 1;
    if (step < 7) {
      int ns = step + 1;
      int nvt = ns >> 2, nks = ns & 3;
      int vb2 = (vtp * 2 + nvt) * 128;
#pragma unroll
      for (int c = 0; c < 2; ++c) {
        int i = wave * 2 + c;
        gload_lds16(&Wv8[(vb2 + i * 16 + (lane >> 2)) * 256 + nks * 64 + (lane & 3) * 16],
                    bufp[buf ^ 1] + i * 1024);
      }
    }
#pragma unroll
    for (int kk = 0; kk < 2; ++kk) {
      long long b[4];
#pragma unroll
      for (int n = 0; n < 4; ++n) {
        int rr = wn * 64 + n * 16 + lr;
        b[n] = *(const long long*)&bufp[buf][rr * 64 + (((kk * 4 + lg) ^ ((rr >> 1) & 7)) << 3)];
      }
      __builtin_amdgcn_s_setprio(1);
#pragma unroll
      for (int m = 0; m < 4; ++m)
#pragma unroll
        for (int n = 0; n < 4; ++n)
          acc[m][n] = __builtin_amdgcn_mfma_f32_16x16x32_fp8_fp8(a_reg[m][ks * 2 + kk], b[n],
                                                                 acc[m][n], 0, 0, 0);
      __builtin_amdgcn_s_setprio(0);
    }
    if (ks == 3) {
      int v0 = (vtp * 2 + vt) * 128;
      float rs[4][4];
#pragma unroll
      for (int m = 0; m < 4; ++m)
#pragma unroll
        for (int g = 0; g < 4; ++g) rs[m][g] = 0.f;
#pragma unroll
      for (int m = 0; m < 4; ++m) {
#pragma unroll
        for (int n = 0; n < 4; ++n) {
          float bvv = bv[v0 + wn * 64 + n * 16 + lr];
#pragma unroll
          for (int g = 0; g < 4; ++g) rs[m][g] += __expf(acc[m][n][g] * SC + bvv);
          acc[m][n] = (f32x4){0.f, 0.f, 0.f, 0.f};
        }
      }
#pragma unroll
      for (int m = 0; m < 4; ++m)
#pragma unroll
        for (int g = 0; g < 4; ++g) {
          float v = rs[m][g];
          v += __shfl_xor(v, 1);
          v += __shfl_xor(v, 2);
          v += __shfl_xor(v, 4);
          v += __shfl_xor(v, 8);
          rs[m][g] = v;
        }
      if (lr == 0) {
#pragma unroll
        for (int m = 0; m < 4; ++m)
#pragma unroll
          for (int g = 0; g < 4; ++g)
            red2[wn * 128 + wm * 64 + m * 16 + lg * 4 + g] = rs[m][g];
      }
      __syncthreads();   // red2 ready; doubles as step-end barrier
      if (t < 128) dpart[(vtp * 2 + vt) * NR + r0 + t] = red2[t] + red2[128 + t];
    } else {
      __syncthreads();   // step-end: next-stage loads drained, guards buffer WAR
    }
  }
}

// ---- reduce partial denominators ----
__global__ void k_reduce(const float* __restrict__ dpart, float* __restrict__ dsum) {
  int r = blockIdx.x * 256 + threadIdx.x;
  float s = 0.f;
  for (int vt = 0; vt < 250; ++vt) s += dpart[vt * NR + r];
  dsum[r] = s;
}

// ---- emission numerators via fp8 MFMA: one 64-thread block per (b,half) ----
__global__ __launch_bounds__(64) void k_emis(const unsigned char* __restrict__ hb8,
                                             const unsigned char* __restrict__ Wv8,
                                             const float* __restrict__ bv,
                                             const float* __restrict__ dsum,
                                             const int* __restrict__ src,
                                             float* __restrict__ em) {
  __shared__ unsigned char A8[48 * 256];
  __shared__ unsigned char B8[48 * 256];
  __shared__ int s_src[48];
  int t = threadIdx.x;
  int bh = blockIdx.x;
  int b = bh & 31, half = bh >> 5;
  int row4 = t >> 4, seg = t & 15;
  int rbase = half * 1536 + b * 48;
  if (t < 48) s_src[t] = src[b * 48 + t];
#pragma unroll
  for (int c = 0; c < 12; ++c) {
    int row = c * 4 + row4;
    gload_lds16(&hb8[(rbase + row) * 256 + seg * 16], &A8[c * 1024]);
    int sv = src[b * 48 + row];
    gload_lds16(&Wv8[sv * 256 + seg * 16], &B8[c * 1024]);
  }
  __syncthreads();
  int lg = t >> 4, lr = t & 15;
  int svr[3];
#pragma unroll
  for (int m = 0; m < 3; ++m) svr[m] = s_src[m * 16 + lr];
  f32x4 acc[3][3];
#pragma unroll
  for (int m = 0; m < 3; ++m)
#pragma unroll
    for (int n = 0; n < 3; ++n) acc[m][n] = (f32x4){0.f, 0.f, 0.f, 0.f};
#pragma unroll
  for (int kk = 0; kk < 8; ++kk) {
    int sa = kk * 4 + lg;          // absolute 8B slot 0..31
    long long a[3], bb[3];
#pragma unroll
    for (int m = 0; m < 3; ++m) {
      int rr = m * 16 + lr;
      a[m] = *(const long long*)&A8[rr * 256 + ((sa ^ lr) << 3)];
      bb[m] = *(const long long*)&B8[rr * 256 + ((sa >> 3) << 6) +
                                     (((sa & 7) ^ ((svr[m] >> 1) & 7)) << 3)];
    }
#pragma unroll
    for (int m = 0; m < 3; ++m)
#pragma unroll
      for (int n = 0; n < 3; ++n)
        acc[m][n] = __builtin_amdgcn_mfma_f32_16x16x32_fp8_fp8(a[m], bb[n], acc[m][n], 0, 0, 0);
  }
  const float SC = 6.103515625e-05f;
#pragma unroll
  for (int n = 0; n < 3; ++n) {
    int i = n * 16 + lr;
    float bvv = bv[svr[n]];
#pragma unroll
    for (int m = 0; m < 3; ++m) {
#pragma unroll
      for (int g = 0; g < 4; ++g) {
        int j = m * 16 + lg * 4 + g;
        float val = __expf(acc[m][n][g] * SC + bvv) / dsum[rbase + j];
        em[b * 4608 + (half * 48 + j) * 48 + i] = val;
      }
    }
  }
}

// ---- fused HMM forward/backward: blocks 0..31 forward(batch), 32..63 backward(batch) ----
__global__ __launch_bounds__(192) void k_fb(const float* __restrict__ Atr, const float* __restrict__ pi,
                                            const float* __restrict__ em, float* __restrict__ alph,
                                            float* __restrict__ betas, float* __restrict__ out1) {
  __shared__ float A_st[96 * 97];
  __shared__ float em_lds[48 * 97];
  __shared__ __align__(16) float vec_lds[96];
  __shared__ float red[3];
  int t = threadIdx.x;
  int bid = blockIdx.x;
  int b = bid & 31;
  int role = bid >> 5;
  int col = t >> 1, half = t & 1;
  int base = b * 4608;

  for (int idx = t; idx < 96 * 96; idx += 192) {
    int s = idx / 96, tt = idx % 96;
    A_st[s * 97 + tt] = Atr[b * 9216 + idx];
  }
  for (int idx = t; idx < 96 * 48; idx += 192) {
    int s = idx / 48, i = idx % 48;
    em_lds[i * 97 + s] = em[base + idx];
  }
  __syncthreads();

  float Areg[48];
  if (role == 0) {
#pragma unroll
    for (int ss = 0; ss < 48; ++ss) Areg[ss] = A_st[(half * 48 + ss) * 97 + col];

    float llsum;
    {
      float v = pi[b * 96 + col] * em_lds[0 * 97 + col];
      float ws = half ? 0.f : v;
      ws = wave_sum(ws);
      if ((t & 63) == 0) red[t >> 6] = ws;
      __syncthreads();
      float c = red[0] + red[1] + red[2];
      float a = v / c;
      if (!half) {
        vec_lds[col] = a;
        alph[base + col] = a;
      }
      llsum = logf(c);
      __syncthreads();
    }
    for (int i = 1; i < 48; ++i) {
      float p = 0.f;
      const float4* ap = (const float4*)&vec_lds[half * 48];
#pragma unroll
      for (int q = 0; q < 12; ++q) {
        float4 av = ap[q];
        p += av.x * Areg[4 * q] + av.y * Areg[4 * q + 1] + av.z * Areg[4 * q + 2] + av.w * Areg[4 * q + 3];
      }
      p += __shfl_xor(p, 1);
      float an = p * em_lds[i * 97 + col];
      float ws = half ? 0.f : an;
      ws = wave_sum(ws);
      if ((t & 63) == 0) red[t >> 6] = ws;
      __syncthreads();
      float c = red[0] + red[1] + red[2];
      float a = an / c;
      if (!half) {
        vec_lds[col] = a;
        alph[base + i * 96 + col] = a;
      }
      llsum += logf(c);
      __syncthreads();
    }
    if (t == 0) out1[b] = -llsum;
  } else {
#pragma unroll
    for (int tt = 0; tt < 48; ++tt) Areg[tt] = A_st[col * 97 + half * 48 + tt];

    if (!half) {
      betas[base + 47 * 96 + col] = 1.0f;
      vec_lds[col] = em_lds[47 * 97 + col];
    }
    __syncthreads();
    for (int i = 46; i >= 0; --i) {
      float p = 0.f;
      const float4* ep = (const float4*)&vec_lds[half * 48];
#pragma unroll
      for (int q = 0; q < 12; ++q) {
        float4 ev = ep[q];
        p += ev.x * Areg[4 * q] + ev.y * Areg[4 * q + 1] + ev.z * Areg[4 * q + 2] + ev.w * Areg[4 * q + 3];
      }
      p += __shfl_xor(p, 1);
      float ws = half ? 0.f : p;
      ws = wave_sum(ws);
      if ((t & 63) == 0) red[t >> 6] = ws;
      __syncthreads();
      float c = red[0] + red[1] + red[2];
      float bt = p / c;
      if (!half) {
        betas[base + i * 96 + col] = bt;
        vec_lds[col] = em_lds[i * 97 + col] * bt;
      }
      __syncthreads();
    }
  }
}

// ---- gamma = alpha*beta, renormalized per (b,i); write transposed [b][s][i] ----
__global__ __launch_bounds__(128) void k_gamma(const float* __restrict__ alph,
                                               const float* __restrict__ betas,
                                               float* __restrict__ out0) {
  __shared__ float red[2];
  int b = blockIdx.x, i = blockIdx.y;
  int t = threadIdx.x;
  float g = 0.f;
  if (t < 96) g = alph[b * 4608 + i * 96 + t] * betas[b * 4608 + i * 96 + t];
  float ws = wave_sum(g);
  if ((t & 63) == 0) red[t >> 6] = ws;
  __syncthreads();
  float c = red[0] + red[1];
  if (t < 96) out0[b * 4608 + t * 48 + i] = g / c;
}

extern "C" void kernel_launch(void* const* d_in, const int* in_sizes, int n_in,
                              void* d_out, int out_size, void* d_ws, size_t ws_size,
                              hipStream_t stream) {
  const float* emb = (const float*)d_in[0];
  const float* Wb  = (const float*)d_in[1];
  const float* Wh  = (const float*)d_in[2];
  const float* bh  = (const float*)d_in[3];
  const float* Wv  = (const float*)d_in[4];
  const float* bv  = (const float*)d_in[5];
  const float* Atr = (const float*)d_in[6];
  const float* pi  = (const float*)d_in[7];
  const int* tc    = (const int*)d_in[8];
  const int* tcn   = (const int*)d_in[9];
  const int* src   = (const int*)d_in[10];

  float* out0 = (float*)d_out;
  float* out1 = out0 + NB * NS * NI;

  char* ws = (char*)d_ws;
  unsigned char* wv8 = (unsigned char*)(ws);                    //  8,192,000 B
  unsigned char* hb8 = (unsigned char*)(ws + 8192000);          //    786,432 B
  float* dpart       = (float*)(ws + 8978432);                  //  3,072,000 B
  float* betas       = (float*)(ws + 8978432);                  //  reuse: dpart dead after k_reduce
  float* dsum        = (float*)(ws + 12050432);                 //     12,288 B
  float* em          = (float*)(ws + 12062720);                 //    589,824 B
  float* alph        = (float*)(ws + 12652544);                 //    589,824 B
  unsigned short* wbt = (unsigned short*)(ws + 13242368);       //    163,840 B
  unsigned short* wht = (unsigned short*)(ws + 13406208);       //     65,536 B
  unsigned short* xb  = (unsigned short*)(ws + 13471744);       //    786,432 B

  k_transpose<<<dim3(500, 4), 256, 0, stream>>>(Wv, wv8);
  k_t2b<<<dim3(10, 2), 256, 0, stream>>>(Wb, wbt, 640, 128);
  k_t2b<<<dim3(2, 4), 256, 0, stream>>>(Wh, wht, 128, 256);
  k_xb<<<96, 256, 0, stream>>>(emb, wbt, tc, tcn, xb);
  k_h<<<dim3(24, 2), 256, 0, stream>>>(xb, wht, bh, hb8);
  k_denom<<<3000, 256, 0, stream>>>(hb8, wv8, bv, dpart);
  k_reduce<<<12, 256, 0, stream>>>(dpart, dsum);
  k_emis<<<64, 64, 0, stream>>>(hb8, wv8, bv, dsum, src, em);
  k_fb<<<64, 192, 0, stream>>>(Atr, pi, em, alph, betas, out1);
  k_gamma<<<dim3(32, 48), 128, 0, stream>>>(alph, betas, out0);
}